// Round 5
// baseline (350.713 us; speedup 1.0000x reference)
//
#include <hip/hip_runtime.h>

// Problem constants (match reference)
constexpr int N_NODES = 100000;
constexpr int N_EDGES = 500000;
constexpr int HID     = 128;   // conv1/conv2 output dim
constexpr int OUT_D   = 64;    // conv3 output dim
constexpr int TOTN    = 2 * N_NODES;   // both networks concatenated

constexpr int ROW_BLKS = (N_NODES + 63) / 64;   // 1563 blocks of 64 rows
constexpr int N_PAD    = ROW_BLKS * 64;          // 100032 padded rows

// ---- CSR build via coarse bucket binning ----
constexpr int BK_LG    = 10;                      // 1024 nodes per bucket
constexpr int BK_W     = 1 << BK_LG;
constexpr int NBUCK    = (TOTN + BK_W - 1) >> BK_LG;   // 196
constexpr int BCAP     = 6144;                    // mean 5120, sigma~72 -> +14 sigma
constexpr int BCAP_PAD = BCAP + 3 * BK_W;         // 9216: room for per-node 4-align padding
constexpr int BIN_TILE = 4096;                    // edges per bin block
constexpr int BIN_NBLK = (2 * N_EDGES + BIN_TILE - 1) / BIN_TILE;  // 245
static_assert(NBUCK <= 256, "bucket scan must fit one block");

typedef __attribute__((ext_vector_type(8))) short short8;
typedef __attribute__((ext_vector_type(4))) float float4v;
typedef __attribute__((ext_vector_type(4))) float f4;
typedef __attribute__((ext_vector_type(4))) int   i4;
typedef __attribute__((ext_vector_type(4))) unsigned u4;

// float -> bf16 (round-to-nearest-even), as raw ushort
__device__ __forceinline__ unsigned short f2bf(float f) {
    unsigned u = __float_as_uint(f);
    u += 0x7fffu + ((u >> 16) & 1u);
    return (unsigned short)(u >> 16);
}
// packed pair of bf16 (lo = even col, hi = odd col) -> two floats
__device__ __forceinline__ float2 bfp2f(unsigned u) {
    float2 r;
    r.x = __uint_as_float(u << 16);
    r.y = __uint_as_float(u & 0xffff0000u);
    return r;
}

__device__ __forceinline__ f4 ntload4f(const float* p) {
    return __builtin_nontemporal_load((const f4*)p);
}
__device__ __forceinline__ i4 ntload4i(const int* p) {
    return __builtin_nontemporal_load((const i4*)p);
}
__device__ __forceinline__ short8 ntload8s(const unsigned short* p) {
    return __builtin_nontemporal_load((const short8*)p);
}

// 8 bf16 (one uint4) scaled-accumulate into acc[0..7] (static indices only)
__device__ __forceinline__ void acc8(float* acc, uint4 u, float nm) {
    const float2 p0 = bfp2f(u.x), p1 = bfp2f(u.y), p2 = bfp2f(u.z), p3 = bfp2f(u.w);
    acc[0] = fmaf(p0.x, nm, acc[0]); acc[1] = fmaf(p0.y, nm, acc[1]);
    acc[2] = fmaf(p1.x, nm, acc[2]); acc[3] = fmaf(p1.y, nm, acc[3]);
    acc[4] = fmaf(p2.x, nm, acc[4]); acc[5] = fmaf(p2.y, nm, acc[5]);
    acc[6] = fmaf(p3.x, nm, acc[6]); acc[7] = fmaf(p3.y, nm, acc[7]);
}

// ================= phase1: bin edges (blocks [0,BIN_NBLK)) + conv1/conv2 GEMM =================
// GEMM blocks pack raw fp32 W into LDS MFMA-B layout themselves (no Wp dependency).
__global__ __launch_bounds__(256) void phase1(const int* __restrict__ s_ei,
                                              const int* __restrict__ t_ei,
                                              int* __restrict__ tail,
                                              uint2* __restrict__ binned,
                                              const float* __restrict__ xs,
                                              const float* __restrict__ xt,
                                              const float* __restrict__ W1,
                                              const float* __restrict__ W2,
                                              unsigned short* __restrict__ Lb1,
                                              unsigned short* __restrict__ Lb2, int n) {
    __shared__ int smem[8192];   // 32 KB, aliased by both branches

    if (blockIdx.x < BIN_NBLK) {
        // -------- bin branch --------
        int* hist = smem;
        int* lcur = smem + NBUCK;
        for (int i = threadIdx.x; i < NBUCK; i += 256) hist[i] = 0;
        __syncthreads();

        const int base_e = blockIdx.x * BIN_TILE;
        int esrc[16], egd[16], ebk[16];
#pragma unroll
        for (int k = 0; k < 16; ++k) {
            const int e = base_e + k * 256 + threadIdx.x;
            int s = 0, g = -1;
            if (e < N_EDGES) {
                s = s_ei[e];
                g = s_ei[N_EDGES + e];
            } else if (e < 2 * N_EDGES) {
                const int j = e - N_EDGES;
                s = t_ei[j];
                g = N_NODES + t_ei[N_EDGES + j];
            }
            esrc[k] = s; egd[k] = g;
            if (g >= 0) { ebk[k] = g >> BK_LG; atomicAdd(&hist[ebk[k]], 1); }
            else ebk[k] = -1;
        }
        __syncthreads();
        for (int i = threadIdx.x; i < NBUCK; i += 256) {
            const int h = hist[i];
            lcur[i] = h ? atomicAdd(&tail[i], h) : 0;
        }
        __syncthreads();
#pragma unroll
        for (int k = 0; k < 16; ++k) {
            if (ebk[k] >= 0) {
                const int p = atomicAdd(&lcur[ebk[k]], 1);
                if (p < BCAP)
                    binned[(size_t)ebk[k] * BCAP + p] = make_uint2((unsigned)esrc[k], (unsigned)egd[k]);
            }
        }
        return;
    }

    // -------- GEMM branch (fp32 A, fused bf16 convert; W packed into LDS in-block) --------
    unsigned short* Bs = (unsigned short*)smem;   // 16*128*8 bf16 = 32 KB
    const int cbid = blockIdx.x - BIN_NBLK;
    const int net  = cbid >= ROW_BLKS;
    const int xb   = net ? cbid - ROW_BLKS : cbid;
    const float* __restrict__ X = net ? xt : xs;
    const float* __restrict__ W = net ? W2 : W1;
    unsigned short* __restrict__ Y = net ? Lb2 : Lb1;

    const int wave = threadIdx.x >> 6;
    const int lane = threadIdx.x & 63;
    const int quad = lane >> 4;
    const int l16  = lane & 15;
    const int rowbase = xb * 64 + wave * 16;
    const int row = rowbase + l16;
    const int rc  = row < n ? row : n - 1;    // clamp: garbage rows never stored

    // issue ALL 8 A-tile loads first (NT: read-once stream)
    f4 f[8];
    const size_t arow = (size_t)rc * 128;
#pragma unroll
    for (int i = 0; i < 8; ++i)
        f[i] = ntload4f(&X[arow + (i >> 1) * 32 + quad * 8 + (i & 1) * 4]);

    // pack W[128,128] fp32 -> LDS MFMA-B bf16 layout (k=kb*32+quad*8+j)
#pragma unroll
    for (int i = 0; i < 16; ++i) {
        const int e0 = (i * 256 + threadIdx.x) * 4;
        const f4 w = ntload4f(W + e0);
        const int k  = e0 >> 7;
        const int nn = e0 & 127;
        const int dst = (((k >> 5) * 4 + ((k & 31) >> 3)) * HID + nn) * 8 + (k & 7);
        Bs[dst + 0]  = f2bf(w[0]);
        Bs[dst + 8]  = f2bf(w[1]);
        Bs[dst + 16] = f2bf(w[2]);
        Bs[dst + 24] = f2bf(w[3]);
    }
    __syncthreads();

    // convert A to bf16 fragments
    short8 a[4];
#pragma unroll
    for (int kb = 0; kb < 4; ++kb) {
        const f4 g0 = f[2 * kb], g1 = f[2 * kb + 1];
        short8 v;
        v[0] = (short)f2bf(g0[0]); v[1] = (short)f2bf(g0[1]);
        v[2] = (short)f2bf(g0[2]); v[3] = (short)f2bf(g0[3]);
        v[4] = (short)f2bf(g1[0]); v[5] = (short)f2bf(g1[1]);
        v[6] = (short)f2bf(g1[2]); v[7] = (short)f2bf(g1[3]);
        a[kb] = v;
    }

#pragma unroll
    for (int ct = 0; ct < HID / 16; ++ct) {
        const int col = ct * 16 + l16;
        float4v acc = {0.0f, 0.0f, 0.0f, 0.0f};
#pragma unroll
        for (int kb = 0; kb < 4; ++kb) {
            const short8 b = *(const short8*)&Bs[((kb * 4 + quad) * HID + col) * 8];
            acc = __builtin_amdgcn_mfma_f32_16x16x32_bf16(a[kb], b, acc, 0, 0, 0);
        }
#pragma unroll
        for (int r = 0; r < 4; ++r) {
            const int orow = rowbase + quad * 4 + r;   // C/D: row=(lane>>4)*4+reg, col=lane&15
            if (orow < n) Y[(size_t)orow * HID + col] = f2bf(acc[r]);   // cacheable: gather target
        }
    }
}

// ---------- P2: per-bucket CSR build (fixed-stride, 4-aligned node segments) ----------
__global__ __launch_bounds__(256) void build_csr(const int* __restrict__ tail,
                                                 const uint2* __restrict__ binned,
                                                 uint4* __restrict__ node_info,
                                                 float* __restrict__ dis,
                                                 int* __restrict__ ebuf) {
    __shared__ int hist[BK_W];
    __shared__ int ssum[256];
    const int b   = blockIdx.x;
    const int t   = threadIdx.x;
    const int gn0 = b << BK_LG;
    const int nn  = min(BK_W, TOTN - gn0);
    const int cnt = min(tail[b], BCAP);
    const int cbase = b * BCAP_PAD;
    const uint2* __restrict__ mine = binned + (size_t)b * BCAP;

    for (int i = t; i < BK_W; i += 256) hist[i] = 0;
    __syncthreads();
    for (int r = t; r < cnt; r += 256)
        atomicAdd(&hist[(int)mine[r].y - gn0], 1);
    __syncthreads();

    // exclusive scan over 1024 PADDED histogram entries (4 per thread, pad to x4)
    const int h0 = hist[t * 4 + 0], h1 = hist[t * 4 + 1];
    const int h2 = hist[t * 4 + 2], h3 = hist[t * 4 + 3];
    const int p0 = (h0 + 3) & ~3, p1 = (h1 + 3) & ~3;
    const int p2 = (h2 + 3) & ~3, p3 = (h3 + 3) & ~3;
    const int ts = p0 + p1 + p2 + p3;
    ssum[t] = ts;
    __syncthreads();
    for (int o = 1; o < 256; o <<= 1) {
        const int x = (t >= o) ? ssum[t - o] : 0;
        __syncthreads();
        if (t >= o) ssum[t] += x;
        __syncthreads();
    }
    const int ex = ssum[t] - ts;
    const int o0 = ex, o1 = ex + p0, o2 = o1 + p1, o3 = o2 + p2;

    // node outputs (coalesced): node_info = {off, deg, bits(dis), 0}
    if (t * 4 + 0 < nn) { const int g = gn0 + t * 4 + 0; const float d = rsqrtf((float)h0 + 1.0f);
        node_info[g] = make_uint4((unsigned)(cbase + o0), (unsigned)h0, __float_as_uint(d), 0u); dis[g] = d; }
    if (t * 4 + 1 < nn) { const int g = gn0 + t * 4 + 1; const float d = rsqrtf((float)h1 + 1.0f);
        node_info[g] = make_uint4((unsigned)(cbase + o1), (unsigned)h1, __float_as_uint(d), 0u); dis[g] = d; }
    if (t * 4 + 2 < nn) { const int g = gn0 + t * 4 + 2; const float d = rsqrtf((float)h2 + 1.0f);
        node_info[g] = make_uint4((unsigned)(cbase + o2), (unsigned)h2, __float_as_uint(d), 0u); dis[g] = d; }
    if (t * 4 + 3 < nn) { const int g = gn0 + t * 4 + 3; const float d = rsqrtf((float)h3 + 1.0f);
        node_info[g] = make_uint4((unsigned)(cbase + o3), (unsigned)h3, __float_as_uint(d), 0u); dis[g] = d; }
    __syncthreads();

    // repurpose hist as running cursors (padded exclusive offsets)
    hist[t * 4 + 0] = o0; hist[t * 4 + 1] = o1; hist[t * 4 + 2] = o2; hist[t * 4 + 3] = o3;
    __syncthreads();

    // scatter into block-local CSR window (single XCD L2)
    for (int r = t; r < cnt; r += 256) {
        const uint2 rec = mine[r];
        const int p = atomicAdd(&hist[(int)rec.y - gn0], 1);
        ebuf[cbase + p] = (int)rec.x;
    }
}

// ---------- MFMA GEMM, bf16 input (conv3); W3 fp32 packed into LDS in-block ----------
__global__ __launch_bounds__(256) void mfma_gemm_bf(const unsigned short* __restrict__ Xb0,
                                                    const unsigned short* __restrict__ Xb1,
                                                    const float* __restrict__ W3,
                                                    unsigned short* __restrict__ Y0,
                                                    unsigned short* __restrict__ Y1, int n) {
    __shared__ unsigned short Bs[16 * OUT_D * 8];   // 16 KB

    const unsigned short* __restrict__ Xb = blockIdx.y ? Xb1 : Xb0;
    unsigned short* __restrict__ Y = blockIdx.y ? Y1 : Y0;

    const int wave = threadIdx.x >> 6;
    const int lane = threadIdx.x & 63;
    const int quad = lane >> 4;
    const int l16  = lane & 15;
    const int rowbase = blockIdx.x * 64 + wave * 16;

    // issue all 4 A loads first (NT: read-once stream)
    short8 a[4];
    const size_t arow = (size_t)(rowbase + l16) * 128;
#pragma unroll
    for (int kb = 0; kb < 4; ++kb)
        a[kb] = ntload8s(&Xb[arow + kb * 32 + quad * 8]);

    // pack W3[128,64] fp32 -> LDS MFMA-B bf16 layout
#pragma unroll
    for (int i = 0; i < 8; ++i) {
        const int e0 = (i * 256 + threadIdx.x) * 4;
        const f4 w = ntload4f(W3 + e0);
        const int k  = e0 >> 6;
        const int nn = e0 & 63;
        const int dst = (((k >> 5) * 4 + ((k & 31) >> 3)) * OUT_D + nn) * 8 + (k & 7);
        Bs[dst + 0]  = f2bf(w[0]);
        Bs[dst + 8]  = f2bf(w[1]);
        Bs[dst + 16] = f2bf(w[2]);
        Bs[dst + 24] = f2bf(w[3]);
    }
    __syncthreads();

#pragma unroll
    for (int ct = 0; ct < OUT_D / 16; ++ct) {
        const int col = ct * 16 + l16;
        float4v acc = {0.0f, 0.0f, 0.0f, 0.0f};
#pragma unroll
        for (int kb = 0; kb < 4; ++kb) {
            const short8 b = *(const short8*)&Bs[((kb * 4 + quad) * OUT_D + col) * 8];
            acc = __builtin_amdgcn_mfma_f32_16x16x32_bf16(a[kb], b, acc, 0, 0, 0);
        }
#pragma unroll
        for (int r = 0; r < 4; ++r) {
            const int row = rowbase + quad * 4 + r;
            if (row < n) Y[(size_t)row * OUT_D + col] = f2bf(acc[r]);   // cacheable: gather target
        }
    }
}

// ---------- gather conv (128-d): 16 lanes/node, 8-deep batches, net-serialized grid ----------
__global__ __launch_bounds__(256) void gather_relu_128_v4(
        const unsigned short* __restrict__ lin0, const unsigned short* __restrict__ lin1,
        const uint4* __restrict__ node_info, const int* __restrict__ ebuf,
        const float* __restrict__ dis,
        const float* __restrict__ bias0, const float* __restrict__ bias1,
        unsigned short* __restrict__ out0, unsigned short* __restrict__ out1, int n) {
    const int nodeBlocks = (n + 15) / 16;
    const int net = blockIdx.x >= nodeBlocks;          // net0 blocks dispatch first
    const int bx  = blockIdx.x - net * nodeBlocks;
    const unsigned short* __restrict__ lin = net ? lin1 : lin0;
    unsigned short* __restrict__ outb = net ? out1 : out0;
    const float* __restrict__ bias = net ? bias1 : bias0;

    const int wave = threadIdx.x >> 6;
    const int lane = threadIdx.x & 63;
    const int grp  = lane >> 4;          // 4 node-groups per wave
    const int l16  = lane & 15;          // 16 lanes x uint4(16B) = 256B row
    const int node = bx * 16 + wave * 4 + grp;
    if (node >= n) return;

    const float* __restrict__ disb = dis + net * n;
    const uint4 ni = node_info[(size_t)net * n + node];
    const int   start = (int)ni.x;
    const int   cnt   = (int)ni.y;
    const float ds    = __uint_as_float(ni.z);
    const float inv   = ds * ds;               // 1/(deg+1)
    const uint4* __restrict__ linv = (const uint4*)lin;   // row stride: 16 uint4

    float acc[8];
    {
        const uint4 su = linv[(size_t)node * 16 + l16];
        const float2 p0 = bfp2f(su.x), p1 = bfp2f(su.y), p2 = bfp2f(su.z), p3 = bfp2f(su.w);
        acc[0] = p0.x * inv; acc[1] = p0.y * inv;
        acc[2] = p1.x * inv; acc[3] = p1.y * inv;
        acc[4] = p2.x * inv; acc[5] = p2.y * inv;
        acc[6] = p3.x * inv; acc[7] = p3.y * inv;
    }

    for (int j = 0; j < cnt; j += 8) {         // 8-deep masked batches
        const int b0 = start + j;              // 4-aligned by construction
        const i4 qa = ntload4i(&ebuf[b0]);     // NT: edge list is read-once
        const i4 qb = ntload4i(&ebuf[b0 + 4]);
        const int s0 = qa[0];
        const int s1 = j + 1 < cnt ? qa[1] : qa[0];
        const int s2 = j + 2 < cnt ? qa[2] : qa[0];
        const int s3 = j + 3 < cnt ? qa[3] : qa[0];
        const int s4 = j + 4 < cnt ? qb[0] : qa[0];
        const int s5 = j + 5 < cnt ? qb[1] : qa[0];
        const int s6 = j + 6 < cnt ? qb[2] : qa[0];
        const int s7 = j + 7 < cnt ? qb[3] : qa[0];
        const float d0 = disb[s0], d1 = disb[s1], d2 = disb[s2], d3 = disb[s3];
        const float d4 = disb[s4], d5 = disb[s5], d6 = disb[s6], d7 = disb[s7];
        const uint4 u0 = linv[(size_t)s0 * 16 + l16];
        const uint4 u1 = linv[(size_t)s1 * 16 + l16];
        const uint4 u2 = linv[(size_t)s2 * 16 + l16];
        const uint4 u3 = linv[(size_t)s3 * 16 + l16];
        const uint4 u4 = linv[(size_t)s4 * 16 + l16];
        const uint4 u5 = linv[(size_t)s5 * 16 + l16];
        const uint4 u6 = linv[(size_t)s6 * 16 + l16];
        const uint4 u7 = linv[(size_t)s7 * 16 + l16];
        const float n0 = d0 * ds;
        const float n1 = j + 1 < cnt ? d1 * ds : 0.0f;
        const float n2 = j + 2 < cnt ? d2 * ds : 0.0f;
        const float n3 = j + 3 < cnt ? d3 * ds : 0.0f;
        const float n4 = j + 4 < cnt ? d4 * ds : 0.0f;
        const float n5 = j + 5 < cnt ? d5 * ds : 0.0f;
        const float n6 = j + 6 < cnt ? d6 * ds : 0.0f;
        const float n7 = j + 7 < cnt ? d7 * ds : 0.0f;
        acc8(acc, u0, n0); acc8(acc, u1, n1); acc8(acc, u2, n2); acc8(acc, u3, n3);
        acc8(acc, u4, n4); acc8(acc, u5, n5); acc8(acc, u6, n6); acc8(acc, u7, n7);
    }

    const float4 bb0 = ((const float4*)bias)[l16 * 2];
    const float4 bb1 = ((const float4*)bias)[l16 * 2 + 1];
    acc[0] += bb0.x; acc[1] += bb0.y; acc[2] += bb0.z; acc[3] += bb0.w;
    acc[4] += bb1.x; acc[5] += bb1.y; acc[6] += bb1.z; acc[7] += bb1.w;
#pragma unroll
    for (int k = 0; k < 8; ++k) acc[k] = acc[k] > 0.0f ? acc[k] : 0.0f;

    u4 pz;
    pz[0] = (unsigned)f2bf(acc[0]) | ((unsigned)f2bf(acc[1]) << 16);
    pz[1] = (unsigned)f2bf(acc[2]) | ((unsigned)f2bf(acc[3]) << 16);
    pz[2] = (unsigned)f2bf(acc[4]) | ((unsigned)f2bf(acc[5]) << 16);
    pz[3] = (unsigned)f2bf(acc[6]) | ((unsigned)f2bf(acc[7]) << 16);
    __builtin_nontemporal_store(pz, (u4*)outb + (size_t)node * 16 + l16);  // NT: don't pollute L2
}

// ---------- gather conv (64-d): 8 lanes/node, 8-deep batches, net-serialized grid ----------
__global__ __launch_bounds__(256) void gather_out_64_v4(
        const unsigned short* __restrict__ lin0, const unsigned short* __restrict__ lin1,
        const uint4* __restrict__ node_info, const int* __restrict__ ebuf,
        const float* __restrict__ dis, const float* __restrict__ bias,
        float* __restrict__ out0, float* __restrict__ out1,
        unsigned short* __restrict__ zb0, unsigned short* __restrict__ zb1, int n) {
    const int nodeBlocks = (n + 31) / 32;
    const int net = blockIdx.x >= nodeBlocks;
    const int bx  = blockIdx.x - net * nodeBlocks;
    const unsigned short* __restrict__ lin = net ? lin1 : lin0;
    float* __restrict__ outp = net ? out1 : out0;
    unsigned short* __restrict__ zb = net ? zb1 : zb0;

    const int wave = threadIdx.x >> 6;
    const int lane = threadIdx.x & 63;
    const int grp  = lane >> 3;          // 8 node-groups per wave
    const int l8   = lane & 7;           // 8 lanes x uint4(16B) = 128B row
    const int node = bx * 32 + wave * 8 + grp;
    if (node >= n) return;

    const float* __restrict__ disb = dis + net * n;
    const uint4 ni = node_info[(size_t)net * n + node];
    const int   start = (int)ni.x;
    const int   cnt   = (int)ni.y;
    const float ds    = __uint_as_float(ni.z);
    const float inv   = ds * ds;
    const uint4* __restrict__ linv = (const uint4*)lin;   // row stride: 8 uint4

    float acc[8];
    {
        const uint4 su = linv[(size_t)node * 8 + l8];
        const float2 p0 = bfp2f(su.x), p1 = bfp2f(su.y), p2 = bfp2f(su.z), p3 = bfp2f(su.w);
        acc[0] = p0.x * inv; acc[1] = p0.y * inv;
        acc[2] = p1.x * inv; acc[3] = p1.y * inv;
        acc[4] = p2.x * inv; acc[5] = p2.y * inv;
        acc[6] = p3.x * inv; acc[7] = p3.y * inv;
    }

    for (int j = 0; j < cnt; j += 8) {
        const int b0 = start + j;
        const i4 qa = ntload4i(&ebuf[b0]);
        const i4 qb = ntload4i(&ebuf[b0 + 4]);
        const int s0 = qa[0];
        const int s1 = j + 1 < cnt ? qa[1] : qa[0];
        const int s2 = j + 2 < cnt ? qa[2] : qa[0];
        const int s3 = j + 3 < cnt ? qa[3] : qa[0];
        const int s4 = j + 4 < cnt ? qb[0] : qa[0];
        const int s5 = j + 5 < cnt ? qb[1] : qa[0];
        const int s6 = j + 6 < cnt ? qb[2] : qa[0];
        const int s7 = j + 7 < cnt ? qb[3] : qa[0];
        const float d0 = disb[s0], d1 = disb[s1], d2 = disb[s2], d3 = disb[s3];
        const float d4 = disb[s4], d5 = disb[s5], d6 = disb[s6], d7 = disb[s7];
        const uint4 u0 = linv[(size_t)s0 * 8 + l8];
        const uint4 u1 = linv[(size_t)s1 * 8 + l8];
        const uint4 u2 = linv[(size_t)s2 * 8 + l8];
        const uint4 u3 = linv[(size_t)s3 * 8 + l8];
        const uint4 u4 = linv[(size_t)s4 * 8 + l8];
        const uint4 u5 = linv[(size_t)s5 * 8 + l8];
        const uint4 u6 = linv[(size_t)s6 * 8 + l8];
        const uint4 u7 = linv[(size_t)s7 * 8 + l8];
        const float n0 = d0 * ds;
        const float n1 = j + 1 < cnt ? d1 * ds : 0.0f;
        const float n2 = j + 2 < cnt ? d2 * ds : 0.0f;
        const float n3 = j + 3 < cnt ? d3 * ds : 0.0f;
        const float n4 = j + 4 < cnt ? d4 * ds : 0.0f;
        const float n5 = j + 5 < cnt ? d5 * ds : 0.0f;
        const float n6 = j + 6 < cnt ? d6 * ds : 0.0f;
        const float n7 = j + 7 < cnt ? d7 * ds : 0.0f;
        acc8(acc, u0, n0); acc8(acc, u1, n1); acc8(acc, u2, n2); acc8(acc, u3, n3);
        acc8(acc, u4, n4); acc8(acc, u5, n5); acc8(acc, u6, n6); acc8(acc, u7, n7);
    }

    const float4 bb0 = ((const float4*)bias)[l8 * 2];
    const float4 bb1 = ((const float4*)bias)[l8 * 2 + 1];
    const float z0 = acc[0] + bb0.x, z1 = acc[1] + bb0.y, z2 = acc[2] + bb0.z, z3 = acc[3] + bb0.w;
    const float z4 = acc[4] + bb1.x, z5 = acc[5] + bb1.y, z6 = acc[6] + bb1.z, z7 = acc[7] + bb1.w;

    f4 w0 = {z0, z1, z2, z3};
    f4 w1 = {z4, z5, z6, z7};
    __builtin_nontemporal_store(w0, (f4*)outp + (size_t)node * 16 + l8 * 2);      // final output
    __builtin_nontemporal_store(w1, (f4*)outp + (size_t)node * 16 + l8 * 2 + 1);

    uint4 pz;   // zb stays cacheable: decoder random-reads it
    pz.x = (unsigned)f2bf(z0) | ((unsigned)f2bf(z1) << 16);
    pz.y = (unsigned)f2bf(z2) | ((unsigned)f2bf(z3) << 16);
    pz.z = (unsigned)f2bf(z4) | ((unsigned)f2bf(z5) << 16);
    pz.w = (unsigned)f2bf(z6) | ((unsigned)f2bf(z7) << 16);
    ((uint4*)zb)[(size_t)node * 8 + l8] = pz;
}

// ---------- decoder (bf16 z), net-serialized grid ----------
__global__ __launch_bounds__(256) void decoder2(
        const unsigned short* __restrict__ Zb0, const unsigned short* __restrict__ Zb1,
        const int* __restrict__ s_ei, const int* __restrict__ t_ei,
        float* __restrict__ out0, float* __restrict__ out1) {
    constexpr int EBLK = (N_EDGES * 8) / 256;          // 15625 blocks per net
    const int net = blockIdx.x >= EBLK;
    const int t2  = (blockIdx.x - net * EBLK) * 256 + threadIdx.x;
    const unsigned short* __restrict__ Zb = net ? Zb1 : Zb0;
    const int* __restrict__ ei = net ? t_ei : s_ei;
    float* __restrict__ op = net ? out1 : out0;

    const int edge = t2 >> 3;   // 8 lanes per edge
    const int lane = t2 & 7;
    if (edge >= N_EDGES) return;
    const int s = __builtin_nontemporal_load(ei + edge);
    const int d = __builtin_nontemporal_load(ei + N_EDGES + edge);
    const uint4 ua = *(const uint4*)&Zb[(size_t)s * OUT_D + lane * 8];
    const uint4 ub = *(const uint4*)&Zb[(size_t)d * OUT_D + lane * 8];
    float p = 0.0f;
    {
        const float2 a0 = bfp2f(ua.x), b0 = bfp2f(ub.x);
        const float2 a1 = bfp2f(ua.y), b1 = bfp2f(ub.y);
        const float2 a2 = bfp2f(ua.z), b2 = bfp2f(ub.z);
        const float2 a3 = bfp2f(ua.w), b3 = bfp2f(ub.w);
        p = fmaf(a0.x, b0.x, p); p = fmaf(a0.y, b0.y, p);
        p = fmaf(a1.x, b1.x, p); p = fmaf(a1.y, b1.y, p);
        p = fmaf(a2.x, b2.x, p); p = fmaf(a2.y, b2.y, p);
        p = fmaf(a3.x, b3.x, p); p = fmaf(a3.y, b3.y, p);
    }
    p += __shfl_down(p, 4, 8);
    p += __shfl_down(p, 2, 8);
    p += __shfl_down(p, 1, 8);
    if (lane == 0) __builtin_nontemporal_store(1.0f / (1.0f + expf(-p)), op + edge);
}

extern "C" void kernel_launch(void* const* d_in, const int* in_sizes, int n_in,
                              void* d_out, int out_size, void* d_ws, size_t ws_size,
                              hipStream_t stream) {
    const float* xs  = (const float*)d_in[0];
    const float* xt  = (const float*)d_in[1];
    const int* s_ei  = (const int*)d_in[2];
    const int* t_ei  = (const int*)d_in[3];
    const float* W1  = (const float*)d_in[4];
    const float* b1  = (const float*)d_in[5];
    const float* W2  = (const float*)d_in[6];
    const float* b2  = (const float*)d_in[7];
    const float* W3  = (const float*)d_in[8];
    const float* b3  = (const float*)d_in[9];

    // workspace layout (~115 MB)
    unsigned short* Lb1 = (unsigned short*)d_ws;                 // NPAD*128 bf16 (lin conv1, net s)
    unsigned short* Lb2 = Lb1 + (size_t)N_PAD * HID;             // NPAD*128 bf16 (lin conv1, net t)
    unsigned short* Hb1 = Lb2 + (size_t)N_PAD * HID;             // NPAD*128 bf16 (h, net s)
    unsigned short* Hb2 = Hb1 + (size_t)N_PAD * HID;             // NPAD*128 bf16 (h, net t)
    // aliases (lifetime-disjoint):
    //   conv3 lin overlays conv1 lin; z overlays h
    //   binned edge records overlay Hb (dead before gather_relu writes Hb)
    unsigned short* L2b1 = Lb1;                                  // NPAD*64 bf16 (lin conv3, s)
    unsigned short* L2b2 = Lb2;
    unsigned short* Zb1  = Hb1;                                  // NPAD*64 bf16 (z copy, s)
    unsigned short* Zb2  = Hb2;
    uint2* binned       = (uint2*)Hb1;                           // NBUCK*BCAP*8B = 9.6 MB
    float* dis          = (float*)(Hb2 + (size_t)N_PAD * HID);   // 2N f
    uint4* node_info    = (uint4*)(dis + TOTN);                  // 2N uint4 (16B aligned)
    int*   ebuf         = (int*)(node_info + TOTN);              // NBUCK*BCAP_PAD + slack
    int*   tail         = ebuf + NBUCK * BCAP_PAD + 8;           // NBUCK i

    float* out = (float*)d_out;
    float* out_zs = out;                                 // N*64
    float* out_zt = out + (size_t)N_NODES * OUT_D;       // N*64
    float* out_ps = out + 2 * (size_t)N_NODES * OUT_D;   // E
    float* out_pt = out_ps + N_EDGES;                    // E

    // ---- phase1: bin edges + conv1/conv2 GEMM fused (independent work, one dispatch) ----
    hipMemsetAsync(tail, 0, NBUCK * sizeof(int), stream);
    phase1<<<BIN_NBLK + 2 * ROW_BLKS, 256, 0, stream>>>(
        s_ei, t_ei, tail, binned, xs, xt, W1, W2, Lb1, Lb2, N_NODES);

    // ---- CSR finalize ----
    build_csr<<<NBUCK, 256, 0, stream>>>(tail, binned, node_info, dis, ebuf);

    // ---- gather + bias + relu, net-serialized 1-D grid ----
    gather_relu_128_v4<<<2 * ((N_NODES + 15) / 16), 256, 0, stream>>>(
        Lb1, Lb2, node_info, ebuf, dis, b1, b2, Hb1, Hb2, N_NODES);

    // ---- conv3 lin: MFMA GEMM (bf16 in), W3 packed in-block ----
    mfma_gemm_bf<<<dim3(ROW_BLKS, 2), 256, 0, stream>>>(
        Hb1, Hb2, W3, L2b1, L2b2, N_NODES);

    // ---- gather -> z (fp32 out) + bf16 copy ----
    gather_out_64_v4<<<2 * ((N_NODES + 31) / 32), 256, 0, stream>>>(
        L2b1, L2b2, node_info, ebuf, dis, b3, out_zs, out_zt, Zb1, Zb2, N_NODES);

    // ---- decoder ----
    decoder2<<<2 * ((N_EDGES * 8) / 256), 256, 0, stream>>>(
        Zb1, Zb2, s_ei, t_ei, out_ps, out_pt);
}

// Round 6
// 331.687 us; speedup vs baseline: 1.0574x; 1.0574x over previous
//
#include <hip/hip_runtime.h>

// Problem constants (match reference)
constexpr int N_NODES = 100000;
constexpr int N_EDGES = 500000;
constexpr int HID     = 128;   // conv1/conv2 output dim
constexpr int OUT_D   = 64;    // conv3 output dim
constexpr int TOTN    = 2 * N_NODES;   // both networks concatenated

constexpr int ROW_BLKS = (N_NODES + 63) / 64;   // 1563 blocks of 64 rows
constexpr int N_PAD    = ROW_BLKS * 64;          // 100032 padded rows

// ---- CSR build via coarse bucket binning ----
constexpr int BK_LG    = 10;                      // 1024 nodes per bucket
constexpr int BK_W     = 1 << BK_LG;
constexpr int NBUCK    = (TOTN + BK_W - 1) >> BK_LG;   // 196
constexpr int BCAP     = 6144;                    // mean 5120, sigma~72 -> +14 sigma
constexpr int BCAP_PAD = BCAP + 3 * BK_W;         // 9216: room for per-node 4-align padding
constexpr int BIN_TILE = 4096;                    // edges per bin block
constexpr int BIN_NBLK = (2 * N_EDGES + BIN_TILE - 1) / BIN_TILE;  // 245
constexpr int PACK_N   = 2 * 128 * HID + 128 * OUT_D;              // 40960 weight elems
constexpr int PACK_BLK = (PACK_N + 255) / 256;                     // 160
static_assert(NBUCK <= 256, "bucket scan must fit one block");

typedef __attribute__((ext_vector_type(8))) short short8;
typedef __attribute__((ext_vector_type(4))) float float4v;
typedef __attribute__((ext_vector_type(4))) float f4;
typedef __attribute__((ext_vector_type(4))) unsigned u4;

// float -> bf16 (round-to-nearest-even), as raw ushort
__device__ __forceinline__ unsigned short f2bf(float f) {
    unsigned u = __float_as_uint(f);
    u += 0x7fffu + ((u >> 16) & 1u);
    return (unsigned short)(u >> 16);
}
// packed pair of bf16 (lo = even col, hi = odd col) -> two floats
__device__ __forceinline__ float2 bfp2f(unsigned u) {
    float2 r;
    r.x = __uint_as_float(u << 16);
    r.y = __uint_as_float(u & 0xffff0000u);
    return r;
}

__device__ __forceinline__ f4 ntload4f(const float* p) {
    return __builtin_nontemporal_load((const f4*)p);
}
__device__ __forceinline__ short8 ntload8s(const unsigned short* p) {
    return __builtin_nontemporal_load((const short8*)p);
}

// 8 bf16 (one uint4) scaled-accumulate into acc[0..7] (static indices only)
__device__ __forceinline__ void acc8(float* acc, uint4 u, float nm) {
    const float2 p0 = bfp2f(u.x), p1 = bfp2f(u.y), p2 = bfp2f(u.z), p3 = bfp2f(u.w);
    acc[0] = fmaf(p0.x, nm, acc[0]); acc[1] = fmaf(p0.y, nm, acc[1]);
    acc[2] = fmaf(p1.x, nm, acc[2]); acc[3] = fmaf(p1.y, nm, acc[3]);
    acc[4] = fmaf(p2.x, nm, acc[4]); acc[5] = fmaf(p2.y, nm, acc[5]);
    acc[6] = fmaf(p3.x, nm, acc[6]); acc[7] = fmaf(p3.y, nm, acc[7]);
}

// ---------- weight packing helper (MFMA B-fragment order, bf16) ----------
__device__ __forceinline__ void pack_one(const float* __restrict__ W,
                                         unsigned short* __restrict__ Wp,
                                         int t, int COLS, int lg) {
    const int k = t >> lg, nn = t & (COLS - 1);
    const int kb = k >> 5, rem = k & 31, quad = rem >> 3, j = rem & 7;
    Wp[((size_t)(kb * 4 + quad) * COLS + nn) * 8 + j] = f2bf(W[t]);
}

// ---------- P1: bin edges into coarse buckets (+ fused weight packing) ----------
__global__ __launch_bounds__(256) void bin_edges(const int* __restrict__ s_ei,
                                                 const int* __restrict__ t_ei,
                                                 int* __restrict__ tail,
                                                 uint2* __restrict__ binned,
                                                 const float* __restrict__ W1,
                                                 const float* __restrict__ W2,
                                                 const float* __restrict__ W3,
                                                 unsigned short* __restrict__ Wp1,
                                                 unsigned short* __restrict__ Wp2,
                                                 unsigned short* __restrict__ W3p) {
    if (blockIdx.x >= BIN_NBLK) {   // fused weight-packing blocks
        const int idx = (blockIdx.x - BIN_NBLK) * 256 + threadIdx.x;
        if (idx < 128 * HID) {
            pack_one(W1, Wp1, idx, HID, 7);
        } else if (idx < 2 * 128 * HID) {
            pack_one(W2, Wp2, idx - 128 * HID, HID, 7);
        } else if (idx < PACK_N) {
            pack_one(W3, W3p, idx - 2 * 128 * HID, OUT_D, 6);
        }
        return;
    }

    __shared__ int hist[NBUCK];
    __shared__ int lcur[NBUCK];
    for (int i = threadIdx.x; i < NBUCK; i += 256) hist[i] = 0;
    __syncthreads();

    const int base_e = blockIdx.x * BIN_TILE;
    int esrc[16], egd[16], ebk[16];
#pragma unroll
    for (int k = 0; k < 16; ++k) {
        const int e = base_e + k * 256 + threadIdx.x;
        int s = 0, g = -1;
        if (e < N_EDGES) {
            s = s_ei[e];
            g = s_ei[N_EDGES + e];
        } else if (e < 2 * N_EDGES) {
            const int j = e - N_EDGES;
            s = t_ei[j];
            g = N_NODES + t_ei[N_EDGES + j];
        }
        esrc[k] = s; egd[k] = g;
        if (g >= 0) { ebk[k] = g >> BK_LG; atomicAdd(&hist[ebk[k]], 1); }
        else ebk[k] = -1;
    }
    __syncthreads();
    // reserve one contiguous range per (block, bucket)
    for (int i = threadIdx.x; i < NBUCK; i += 256) {
        const int h = hist[i];
        lcur[i] = h ? atomicAdd(&tail[i], h) : 0;
    }
    __syncthreads();
#pragma unroll
    for (int k = 0; k < 16; ++k) {
        if (ebk[k] >= 0) {
            const int p = atomicAdd(&lcur[ebk[k]], 1);     // LDS atomic -> global pos
            if (p < BCAP)
                binned[(size_t)ebk[k] * BCAP + p] = make_uint2((unsigned)esrc[k], (unsigned)egd[k]);
        }
    }
}

// ---------- P2: per-bucket CSR build (fixed-stride, 4-aligned node segments) ----------
__global__ __launch_bounds__(256) void build_csr(const int* __restrict__ tail,
                                                 const uint2* __restrict__ binned,
                                                 uint4* __restrict__ node_info,
                                                 float* __restrict__ dis,
                                                 int* __restrict__ ebuf) {
    __shared__ int hist[BK_W];
    __shared__ int ssum[256];
    const int b   = blockIdx.x;
    const int t   = threadIdx.x;
    const int gn0 = b << BK_LG;
    const int nn  = min(BK_W, TOTN - gn0);
    const int cnt = min(tail[b], BCAP);
    const int cbase = b * BCAP_PAD;
    const uint2* __restrict__ mine = binned + (size_t)b * BCAP;

    for (int i = t; i < BK_W; i += 256) hist[i] = 0;
    __syncthreads();
    for (int r = t; r < cnt; r += 256)
        atomicAdd(&hist[(int)mine[r].y - gn0], 1);
    __syncthreads();

    // exclusive scan over 1024 PADDED histogram entries (4 per thread, pad to x4)
    const int h0 = hist[t * 4 + 0], h1 = hist[t * 4 + 1];
    const int h2 = hist[t * 4 + 2], h3 = hist[t * 4 + 3];
    const int p0 = (h0 + 3) & ~3, p1 = (h1 + 3) & ~3;
    const int p2 = (h2 + 3) & ~3, p3 = (h3 + 3) & ~3;
    const int ts = p0 + p1 + p2 + p3;
    ssum[t] = ts;
    __syncthreads();
    for (int o = 1; o < 256; o <<= 1) {
        const int x = (t >= o) ? ssum[t - o] : 0;
        __syncthreads();
        if (t >= o) ssum[t] += x;
        __syncthreads();
    }
    const int ex = ssum[t] - ts;
    const int o0 = ex, o1 = ex + p0, o2 = o1 + p1, o3 = o2 + p2;

    // node outputs (coalesced): node_info = {off, deg, bits(dis), 0}
    if (t * 4 + 0 < nn) { const int g = gn0 + t * 4 + 0; const float d = rsqrtf((float)h0 + 1.0f);
        node_info[g] = make_uint4((unsigned)(cbase + o0), (unsigned)h0, __float_as_uint(d), 0u); dis[g] = d; }
    if (t * 4 + 1 < nn) { const int g = gn0 + t * 4 + 1; const float d = rsqrtf((float)h1 + 1.0f);
        node_info[g] = make_uint4((unsigned)(cbase + o1), (unsigned)h1, __float_as_uint(d), 0u); dis[g] = d; }
    if (t * 4 + 2 < nn) { const int g = gn0 + t * 4 + 2; const float d = rsqrtf((float)h2 + 1.0f);
        node_info[g] = make_uint4((unsigned)(cbase + o2), (unsigned)h2, __float_as_uint(d), 0u); dis[g] = d; }
    if (t * 4 + 3 < nn) { const int g = gn0 + t * 4 + 3; const float d = rsqrtf((float)h3 + 1.0f);
        node_info[g] = make_uint4((unsigned)(cbase + o3), (unsigned)h3, __float_as_uint(d), 0u); dis[g] = d; }
    __syncthreads();

    // repurpose hist as running cursors (padded exclusive offsets)
    hist[t * 4 + 0] = o0; hist[t * 4 + 1] = o1; hist[t * 4 + 2] = o2; hist[t * 4 + 3] = o3;
    __syncthreads();

    // scatter into block-local CSR window (single XCD L2)
    for (int r = t; r < cnt; r += 256) {
        const uint2 rec = mine[r];
        const int p = atomicAdd(&hist[(int)rec.y - gn0], 1);
        ebuf[cbase + p] = (int)rec.x;
    }
}

// ---------- MFMA GEMM, fp32 A (NT) with fused bf16 convert; packed B staged in LDS ----------
template <int COLS>
__global__ __launch_bounds__(256) void mfma_gemm_f32(const float* __restrict__ X0,
                                                     const float* __restrict__ X1,
                                                     const unsigned short* __restrict__ Wp0,
                                                     const unsigned short* __restrict__ Wp1,
                                                     unsigned short* __restrict__ Y0,
                                                     unsigned short* __restrict__ Y1, int n) {
    __shared__ unsigned short Bs[16 * COLS * 8];   // full packed W: 32 KB (128) / 16 KB (64)

    const float* __restrict__ X = blockIdx.y ? X1 : X0;
    const unsigned short* __restrict__ Wp = blockIdx.y ? Wp1 : Wp0;
    unsigned short* __restrict__ Y = blockIdx.y ? Y1 : Y0;

    const int wave = threadIdx.x >> 6;
    const int lane = threadIdx.x & 63;
    const int quad = lane >> 4;
    const int l16  = lane & 15;
    const int rowbase = blockIdx.x * 64 + wave * 16;
    const int row = rowbase + l16;
    const int rc  = row < n ? row : n - 1;    // clamp: garbage rows never stored

    // issue ALL 8 A-tile loads first (NT: X is read exactly once)
    f4 f[8];
    const size_t arow = (size_t)rc * 128;
#pragma unroll
    for (int i = 0; i < 8; ++i)
        f[i] = ntload4f(&X[arow + (i >> 1) * 32 + quad * 8 + (i & 1) * 4]);

    // stage packed W into LDS (uint4 copies: conflict-free)
    {
        const uint4* __restrict__ wsrc = (const uint4*)Wp;
        uint4* __restrict__ wdst = (uint4*)Bs;
        constexpr int CH = 16 * COLS;              // 16B chunks
#pragma unroll
        for (int i = 0; i < CH / 256; ++i)
            wdst[i * 256 + threadIdx.x] = wsrc[i * 256 + threadIdx.x];
    }
    __syncthreads();

    // convert A to bf16 fragments
    short8 a[4];
#pragma unroll
    for (int kb = 0; kb < 4; ++kb) {
        const f4 g0 = f[2 * kb], g1 = f[2 * kb + 1];
        short8 v;
        v[0] = (short)f2bf(g0[0]); v[1] = (short)f2bf(g0[1]);
        v[2] = (short)f2bf(g0[2]); v[3] = (short)f2bf(g0[3]);
        v[4] = (short)f2bf(g1[0]); v[5] = (short)f2bf(g1[1]);
        v[6] = (short)f2bf(g1[2]); v[7] = (short)f2bf(g1[3]);
        a[kb] = v;
    }

#pragma unroll
    for (int ct = 0; ct < COLS / 16; ++ct) {
        const int col = ct * 16 + l16;
        float4v acc = {0.0f, 0.0f, 0.0f, 0.0f};
#pragma unroll
        for (int kb = 0; kb < 4; ++kb) {
            const short8 b = *(const short8*)&Bs[((kb * 4 + quad) * COLS + col) * 8];
            acc = __builtin_amdgcn_mfma_f32_16x16x32_bf16(a[kb], b, acc, 0, 0, 0);
        }
#pragma unroll
        for (int r = 0; r < 4; ++r) {
            const int orow = rowbase + quad * 4 + r;   // C/D: row=(lane>>4)*4+reg, col=lane&15
            if (orow < n) Y[(size_t)orow * COLS + col] = f2bf(acc[r]);   // cacheable: gather target
        }
    }
}

// ---------- MFMA GEMM, bf16 input (conv3, NT A reads); packed B staged in LDS ----------
template <int COLS>
__global__ __launch_bounds__(256) void mfma_gemm_bf(const unsigned short* __restrict__ Xb0,
                                                    const unsigned short* __restrict__ Xb1,
                                                    const unsigned short* __restrict__ Wp,
                                                    unsigned short* __restrict__ Y0,
                                                    unsigned short* __restrict__ Y1, int n) {
    __shared__ unsigned short Bs[16 * COLS * 8];

    const unsigned short* __restrict__ Xb = blockIdx.y ? Xb1 : Xb0;
    unsigned short* __restrict__ Y = blockIdx.y ? Y1 : Y0;

    const int wave = threadIdx.x >> 6;
    const int lane = threadIdx.x & 63;
    const int quad = lane >> 4;
    const int l16  = lane & 15;
    const int rowbase = blockIdx.x * 64 + wave * 16;

    // issue all 4 A loads first (NT: this kernel is Hb's last consumer)
    short8 a[4];
    const size_t arow = (size_t)(rowbase + l16) * 128;
#pragma unroll
    for (int kb = 0; kb < 4; ++kb)
        a[kb] = ntload8s(&Xb[arow + kb * 32 + quad * 8]);

    // stage packed W into LDS
    {
        const uint4* __restrict__ wsrc = (const uint4*)Wp;
        uint4* __restrict__ wdst = (uint4*)Bs;
        constexpr int CH = 16 * COLS;
#pragma unroll
        for (int i = 0; i < CH / 256; ++i)
            wdst[i * 256 + threadIdx.x] = wsrc[i * 256 + threadIdx.x];
    }
    __syncthreads();

#pragma unroll
    for (int ct = 0; ct < COLS / 16; ++ct) {
        const int col = ct * 16 + l16;
        float4v acc = {0.0f, 0.0f, 0.0f, 0.0f};
#pragma unroll
        for (int kb = 0; kb < 4; ++kb) {
            const short8 b = *(const short8*)&Bs[((kb * 4 + quad) * COLS + col) * 8];
            acc = __builtin_amdgcn_mfma_f32_16x16x32_bf16(a[kb], b, acc, 0, 0, 0);
        }
#pragma unroll
        for (int r = 0; r < 4; ++r) {
            const int row = rowbase + quad * 4 + r;
            if (row < n) Y[(size_t)row * COLS + col] = f2bf(acc[r]);   // cacheable: gather target
        }
    }
}

// ---------- gather conv (128-d): 16 lanes/node, 8-deep batches, net-serialized grid ----------
__global__ __launch_bounds__(256) void gather_relu_128_v4(
        const unsigned short* __restrict__ lin0, const unsigned short* __restrict__ lin1,
        const uint4* __restrict__ node_info, const int* __restrict__ ebuf,
        const float* __restrict__ dis,
        const float* __restrict__ bias0, const float* __restrict__ bias1,
        unsigned short* __restrict__ out0, unsigned short* __restrict__ out1, int n) {
    const int nodeBlocks = (n + 15) / 16;
    const int net = blockIdx.x >= nodeBlocks;          // net0 blocks dispatch first
    const int bx  = blockIdx.x - net * nodeBlocks;
    const unsigned short* __restrict__ lin = net ? lin1 : lin0;
    unsigned short* __restrict__ outb = net ? out1 : out0;
    const float* __restrict__ bias = net ? bias1 : bias0;

    const int wave = threadIdx.x >> 6;
    const int lane = threadIdx.x & 63;
    const int grp  = lane >> 4;          // 4 node-groups per wave
    const int l16  = lane & 15;          // 16 lanes x uint4(16B) = 256B row
    const int node = bx * 16 + wave * 4 + grp;
    if (node >= n) return;

    const float* __restrict__ disb = dis + net * n;
    const uint4 ni = node_info[(size_t)net * n + node];
    const int   start = (int)ni.x;
    const int   cnt   = (int)ni.y;
    const float ds    = __uint_as_float(ni.z);
    const float inv   = ds * ds;               // 1/(deg+1)
    const uint4* __restrict__ linv = (const uint4*)lin;   // row stride: 16 uint4

    float acc[8];
    {
        const uint4 su = linv[(size_t)node * 16 + l16];
        const float2 p0 = bfp2f(su.x), p1 = bfp2f(su.y), p2 = bfp2f(su.z), p3 = bfp2f(su.w);
        acc[0] = p0.x * inv; acc[1] = p0.y * inv;
        acc[2] = p1.x * inv; acc[3] = p1.y * inv;
        acc[4] = p2.x * inv; acc[5] = p2.y * inv;
        acc[6] = p3.x * inv; acc[7] = p3.y * inv;
    }

    for (int j = 0; j < cnt; j += 8) {         // 8-deep masked batches
        const int b0 = start + j;              // 4-aligned by construction
        const int4 qa = *(const int4*)&ebuf[b0];     // cacheable: re-read by gather_out
        const int4 qb = *(const int4*)&ebuf[b0 + 4];
        const int s0 = qa.x;
        const int s1 = j + 1 < cnt ? qa.y : qa.x;
        const int s2 = j + 2 < cnt ? qa.z : qa.x;
        const int s3 = j + 3 < cnt ? qa.w : qa.x;
        const int s4 = j + 4 < cnt ? qb.x : qa.x;
        const int s5 = j + 5 < cnt ? qb.y : qa.x;
        const int s6 = j + 6 < cnt ? qb.z : qa.x;
        const int s7 = j + 7 < cnt ? qb.w : qa.x;
        const float d0 = disb[s0], d1 = disb[s1], d2 = disb[s2], d3 = disb[s3];
        const float d4 = disb[s4], d5 = disb[s5], d6 = disb[s6], d7 = disb[s7];
        const uint4 u0 = linv[(size_t)s0 * 16 + l16];
        const uint4 u1 = linv[(size_t)s1 * 16 + l16];
        const uint4 u2 = linv[(size_t)s2 * 16 + l16];
        const uint4 u3 = linv[(size_t)s3 * 16 + l16];
        const uint4 u4 = linv[(size_t)s4 * 16 + l16];
        const uint4 u5 = linv[(size_t)s5 * 16 + l16];
        const uint4 u6 = linv[(size_t)s6 * 16 + l16];
        const uint4 u7 = linv[(size_t)s7 * 16 + l16];
        const float n0 = d0 * ds;
        const float n1 = j + 1 < cnt ? d1 * ds : 0.0f;
        const float n2 = j + 2 < cnt ? d2 * ds : 0.0f;
        const float n3 = j + 3 < cnt ? d3 * ds : 0.0f;
        const float n4 = j + 4 < cnt ? d4 * ds : 0.0f;
        const float n5 = j + 5 < cnt ? d5 * ds : 0.0f;
        const float n6 = j + 6 < cnt ? d6 * ds : 0.0f;
        const float n7 = j + 7 < cnt ? d7 * ds : 0.0f;
        acc8(acc, u0, n0); acc8(acc, u1, n1); acc8(acc, u2, n2); acc8(acc, u3, n3);
        acc8(acc, u4, n4); acc8(acc, u5, n5); acc8(acc, u6, n6); acc8(acc, u7, n7);
    }

    const float4 bb0 = ((const float4*)bias)[l16 * 2];
    const float4 bb1 = ((const float4*)bias)[l16 * 2 + 1];
    acc[0] += bb0.x; acc[1] += bb0.y; acc[2] += bb0.z; acc[3] += bb0.w;
    acc[4] += bb1.x; acc[5] += bb1.y; acc[6] += bb1.z; acc[7] += bb1.w;
#pragma unroll
    for (int k = 0; k < 8; ++k) acc[k] = acc[k] > 0.0f ? acc[k] : 0.0f;

    uint4 pz;   // cacheable store: Hb is re-read by conv3 GEMM
    pz.x = (unsigned)f2bf(acc[0]) | ((unsigned)f2bf(acc[1]) << 16);
    pz.y = (unsigned)f2bf(acc[2]) | ((unsigned)f2bf(acc[3]) << 16);
    pz.z = (unsigned)f2bf(acc[4]) | ((unsigned)f2bf(acc[5]) << 16);
    pz.w = (unsigned)f2bf(acc[6]) | ((unsigned)f2bf(acc[7]) << 16);
    ((uint4*)outb)[(size_t)node * 16 + l16] = pz;
}

// ---------- gather conv (64-d): 8 lanes/node, 8-deep batches, net-serialized grid ----------
__global__ __launch_bounds__(256) void gather_out_64_v4(
        const unsigned short* __restrict__ lin0, const unsigned short* __restrict__ lin1,
        const uint4* __restrict__ node_info, const int* __restrict__ ebuf,
        const float* __restrict__ dis, const float* __restrict__ bias,
        float* __restrict__ out0, float* __restrict__ out1,
        unsigned short* __restrict__ zb0, unsigned short* __restrict__ zb1, int n) {
    const int nodeBlocks = (n + 31) / 32;
    const int net = blockIdx.x >= nodeBlocks;
    const int bx  = blockIdx.x - net * nodeBlocks;
    const unsigned short* __restrict__ lin = net ? lin1 : lin0;
    float* __restrict__ outp = net ? out1 : out0;
    unsigned short* __restrict__ zb = net ? zb1 : zb0;

    const int wave = threadIdx.x >> 6;
    const int lane = threadIdx.x & 63;
    const int grp  = lane >> 3;          // 8 node-groups per wave
    const int l8   = lane & 7;           // 8 lanes x uint4(16B) = 128B row
    const int node = bx * 32 + wave * 8 + grp;
    if (node >= n) return;

    const float* __restrict__ disb = dis + net * n;
    const uint4 ni = node_info[(size_t)net * n + node];
    const int   start = (int)ni.x;
    const int   cnt   = (int)ni.y;
    const float ds    = __uint_as_float(ni.z);
    const float inv   = ds * ds;
    const uint4* __restrict__ linv = (const uint4*)lin;   // row stride: 8 uint4

    float acc[8];
    {
        const uint4 su = linv[(size_t)node * 8 + l8];
        const float2 p0 = bfp2f(su.x), p1 = bfp2f(su.y), p2 = bfp2f(su.z), p3 = bfp2f(su.w);
        acc[0] = p0.x * inv; acc[1] = p0.y * inv;
        acc[2] = p1.x * inv; acc[3] = p1.y * inv;
        acc[4] = p2.x * inv; acc[5] = p2.y * inv;
        acc[6] = p3.x * inv; acc[7] = p3.y * inv;
    }

    for (int j = 0; j < cnt; j += 8) {
        const int b0 = start + j;
        const int4 qa = *(const int4*)&ebuf[b0];
        const int4 qb = *(const int4*)&ebuf[b0 + 4];
        const int s0 = qa.x;
        const int s1 = j + 1 < cnt ? qa.y : qa.x;
        const int s2 = j + 2 < cnt ? qa.z : qa.x;
        const int s3 = j + 3 < cnt ? qa.w : qa.x;
        const int s4 = j + 4 < cnt ? qb.x : qa.x;
        const int s5 = j + 5 < cnt ? qb.y : qa.x;
        const int s6 = j + 6 < cnt ? qb.z : qa.x;
        const int s7 = j + 7 < cnt ? qb.w : qa.x;
        const float d0 = disb[s0], d1 = disb[s1], d2 = disb[s2], d3 = disb[s3];
        const float d4 = disb[s4], d5 = disb[s5], d6 = disb[s6], d7 = disb[s7];
        const uint4 u0 = linv[(size_t)s0 * 8 + l8];
        const uint4 u1 = linv[(size_t)s1 * 8 + l8];
        const uint4 u2 = linv[(size_t)s2 * 8 + l8];
        const uint4 u3 = linv[(size_t)s3 * 8 + l8];
        const uint4 u4 = linv[(size_t)s4 * 8 + l8];
        const uint4 u5 = linv[(size_t)s5 * 8 + l8];
        const uint4 u6 = linv[(size_t)s6 * 8 + l8];
        const uint4 u7 = linv[(size_t)s7 * 8 + l8];
        const float n0 = d0 * ds;
        const float n1 = j + 1 < cnt ? d1 * ds : 0.0f;
        const float n2 = j + 2 < cnt ? d2 * ds : 0.0f;
        const float n3 = j + 3 < cnt ? d3 * ds : 0.0f;
        const float n4 = j + 4 < cnt ? d4 * ds : 0.0f;
        const float n5 = j + 5 < cnt ? d5 * ds : 0.0f;
        const float n6 = j + 6 < cnt ? d6 * ds : 0.0f;
        const float n7 = j + 7 < cnt ? d7 * ds : 0.0f;
        acc8(acc, u0, n0); acc8(acc, u1, n1); acc8(acc, u2, n2); acc8(acc, u3, n3);
        acc8(acc, u4, n4); acc8(acc, u5, n5); acc8(acc, u6, n6); acc8(acc, u7, n7);
    }

    const float4 bb0 = ((const float4*)bias)[l8 * 2];
    const float4 bb1 = ((const float4*)bias)[l8 * 2 + 1];
    const float z0 = acc[0] + bb0.x, z1 = acc[1] + bb0.y, z2 = acc[2] + bb0.z, z3 = acc[3] + bb0.w;
    const float z4 = acc[4] + bb1.x, z5 = acc[5] + bb1.y, z6 = acc[6] + bb1.z, z7 = acc[7] + bb1.w;

    f4 w0 = {z0, z1, z2, z3};
    f4 w1 = {z4, z5, z6, z7};
    __builtin_nontemporal_store(w0, (f4*)outp + (size_t)node * 16 + l8 * 2);      // final output
    __builtin_nontemporal_store(w1, (f4*)outp + (size_t)node * 16 + l8 * 2 + 1);

    uint4 pz;   // zb cacheable: decoder random-reads it
    pz.x = (unsigned)f2bf(z0) | ((unsigned)f2bf(z1) << 16);
    pz.y = (unsigned)f2bf(z2) | ((unsigned)f2bf(z3) << 16);
    pz.z = (unsigned)f2bf(z4) | ((unsigned)f2bf(z5) << 16);
    pz.w = (unsigned)f2bf(z6) | ((unsigned)f2bf(z7) << 16);
    ((uint4*)zb)[(size_t)node * 8 + l8] = pz;
}

// ---------- decoder (bf16 z), net-serialized grid ----------
__global__ __launch_bounds__(256) void decoder2(
        const unsigned short* __restrict__ Zb0, const unsigned short* __restrict__ Zb1,
        const int* __restrict__ s_ei, const int* __restrict__ t_ei,
        float* __restrict__ out0, float* __restrict__ out1) {
    constexpr int EBLK = (N_EDGES * 8) / 256;          // 15625 blocks per net
    const int net = blockIdx.x >= EBLK;
    const int t2  = (blockIdx.x - net * EBLK) * 256 + threadIdx.x;
    const unsigned short* __restrict__ Zb = net ? Zb1 : Zb0;
    const int* __restrict__ ei = net ? t_ei : s_ei;
    float* __restrict__ op = net ? out1 : out0;

    const int edge = t2 >> 3;   // 8 lanes per edge
    const int lane = t2 & 7;
    if (edge >= N_EDGES) return;
    const int s = __builtin_nontemporal_load(ei + edge);
    const int d = __builtin_nontemporal_load(ei + N_EDGES + edge);
    const uint4 ua = *(const uint4*)&Zb[(size_t)s * OUT_D + lane * 8];
    const uint4 ub = *(const uint4*)&Zb[(size_t)d * OUT_D + lane * 8];
    float p = 0.0f;
    {
        const float2 a0 = bfp2f(ua.x), b0 = bfp2f(ub.x);
        const float2 a1 = bfp2f(ua.y), b1 = bfp2f(ub.y);
        const float2 a2 = bfp2f(ua.z), b2 = bfp2f(ub.z);
        const float2 a3 = bfp2f(ua.w), b3 = bfp2f(ub.w);
        p = fmaf(a0.x, b0.x, p); p = fmaf(a0.y, b0.y, p);
        p = fmaf(a1.x, b1.x, p); p = fmaf(a1.y, b1.y, p);
        p = fmaf(a2.x, b2.x, p); p = fmaf(a2.y, b2.y, p);
        p = fmaf(a3.x, b3.x, p); p = fmaf(a3.y, b3.y, p);
    }
    p += __shfl_down(p, 4, 8);
    p += __shfl_down(p, 2, 8);
    p += __shfl_down(p, 1, 8);
    if (lane == 0) __builtin_nontemporal_store(1.0f / (1.0f + expf(-p)), op + edge);
}

extern "C" void kernel_launch(void* const* d_in, const int* in_sizes, int n_in,
                              void* d_out, int out_size, void* d_ws, size_t ws_size,
                              hipStream_t stream) {
    const float* xs  = (const float*)d_in[0];
    const float* xt  = (const float*)d_in[1];
    const int* s_ei  = (const int*)d_in[2];
    const int* t_ei  = (const int*)d_in[3];
    const float* W1  = (const float*)d_in[4];
    const float* b1  = (const float*)d_in[5];
    const float* W2  = (const float*)d_in[6];
    const float* b2  = (const float*)d_in[7];
    const float* W3  = (const float*)d_in[8];
    const float* b3  = (const float*)d_in[9];

    // workspace layout (~115 MB)
    unsigned short* Lb1 = (unsigned short*)d_ws;                 // NPAD*128 bf16 (lin conv1, net s)
    unsigned short* Lb2 = Lb1 + (size_t)N_PAD * HID;             // NPAD*128 bf16 (lin conv1, net t)
    unsigned short* Hb1 = Lb2 + (size_t)N_PAD * HID;             // NPAD*128 bf16 (h, net s)
    unsigned short* Hb2 = Hb1 + (size_t)N_PAD * HID;             // NPAD*128 bf16 (h, net t)
    // aliases (lifetime-disjoint):
    //   conv3 lin overlays conv1 lin; z overlays h
    //   binned edge records overlay Hb (dead before gather_relu writes Hb)
    unsigned short* L2b1 = Lb1;                                  // NPAD*64 bf16 (lin conv3, s)
    unsigned short* L2b2 = Lb2;
    unsigned short* Zb1  = Hb1;                                  // NPAD*64 bf16 (z copy, s)
    unsigned short* Zb2  = Hb2;
    uint2* binned       = (uint2*)Hb1;                           // NBUCK*BCAP*8B = 9.6 MB
    unsigned short* Wp1 = Hb2 + (size_t)N_PAD * HID;             // 128*128 bf16
    unsigned short* Wp2 = Wp1 + 128 * HID;                       // 128*128 bf16
    unsigned short* W3p = Wp2 + 128 * HID;                       // 128*64 bf16
    float* dis          = (float*)(W3p + 128 * OUT_D);           // 2N f
    uint4* node_info    = (uint4*)(dis + TOTN);                  // 2N uint4
    int*   ebuf         = (int*)(node_info + TOTN);              // NBUCK*BCAP_PAD + slack
    int*   tail         = ebuf + NBUCK * BCAP_PAD + 8;           // NBUCK i

    float* out = (float*)d_out;
    float* out_zs = out;                                 // N*64
    float* out_zt = out + (size_t)N_NODES * OUT_D;       // N*64
    float* out_ps = out + 2 * (size_t)N_NODES * OUT_D;   // E
    float* out_pt = out_ps + N_EDGES;                    // E

    // ---- CSR build via bucket binning (+ fused weight pack) ----
    hipMemsetAsync(tail, 0, NBUCK * sizeof(int), stream);
    bin_edges<<<BIN_NBLK + PACK_BLK, 256, 0, stream>>>(s_ei, t_ei, tail, binned,
                                                       W1, W2, W3, Wp1, Wp2, W3p);
    build_csr<<<NBUCK, 256, 0, stream>>>(tail, binned, node_info, dis, ebuf);

    // ---- conv1/conv2 lin: fused fp32->bf16 convert + MFMA GEMM, both nets ----
    mfma_gemm_f32<HID><<<dim3(ROW_BLKS, 2), 256, 0, stream>>>(
        xs, xt, Wp1, Wp2, Lb1, Lb2, N_NODES);

    // ---- gather + bias + relu, net-serialized 1-D grid ----
    gather_relu_128_v4<<<2 * ((N_NODES + 15) / 16), 256, 0, stream>>>(
        Lb1, Lb2, node_info, ebuf, dis, b1, b2, Hb1, Hb2, N_NODES);

    // ---- conv3 lin: MFMA GEMM (bf16 in, NT reads), both nets ----
    mfma_gemm_bf<OUT_D><<<dim3(ROW_BLKS, 2), 256, 0, stream>>>(
        Hb1, Hb2, W3p, L2b1, L2b2, N_NODES);

    // ---- gather -> z (fp32 out) + bf16 copy ----
    gather_out_64_v4<<<2 * ((N_NODES + 31) / 32), 256, 0, stream>>>(
        L2b1, L2b2, node_info, ebuf, dis, b3, out_zs, out_zt, Zb1, Zb2, N_NODES);

    // ---- decoder ----
    decoder2<<<2 * ((N_EDGES * 8) / 256), 256, 0, stream>>>(
        Zb1, Zb2, s_ei, t_ei, out_ps, out_pt);
}

// Round 7
// 318.740 us; speedup vs baseline: 1.1003x; 1.0406x over previous
//
#include <hip/hip_runtime.h>

// Problem constants (match reference)
constexpr int N_NODES = 100000;
constexpr int N_EDGES = 500000;
constexpr int HID     = 128;   // conv1/conv2 output dim
constexpr int OUT_D   = 64;    // conv3 output dim
constexpr int TOTN    = 2 * N_NODES;   // both networks concatenated

constexpr int ROW_BLKS = (N_NODES + 63) / 64;   // 1563 blocks of 64 rows
constexpr int N_PAD    = ROW_BLKS * 64;          // 100032 padded rows
static_assert(N_NODES % 16 == 0, "fused gather+MM needs exact 16-node blocks");

// ---- CSR build via coarse bucket binning ----
constexpr int BK_LG    = 10;                      // 1024 nodes per bucket
constexpr int BK_W     = 1 << BK_LG;
constexpr int NBUCK    = (TOTN + BK_W - 1) >> BK_LG;   // 196
constexpr int BCAP     = 6144;                    // mean 5120, sigma~72 -> +14 sigma
constexpr int BCAP_PAD = BCAP + 3 * BK_W;         // 9216: room for per-node 4-align padding
constexpr int BIN_TILE = 4096;                    // edges per bin block
constexpr int BIN_NBLK = (2 * N_EDGES + BIN_TILE - 1) / BIN_TILE;  // 245
constexpr int PACK_N   = 2 * 128 * HID + 128 * OUT_D;              // 40960 weight elems
constexpr int PACK_BLK = (PACK_N + 255) / 256;                     // 160
static_assert(NBUCK <= 256, "bucket scan must fit one block");

typedef __attribute__((ext_vector_type(8))) short short8;
typedef __attribute__((ext_vector_type(4))) float float4v;
typedef __attribute__((ext_vector_type(4))) float f4;

// float -> bf16 (round-to-nearest-even), as raw ushort
__device__ __forceinline__ unsigned short f2bf(float f) {
    unsigned u = __float_as_uint(f);
    u += 0x7fffu + ((u >> 16) & 1u);
    return (unsigned short)(u >> 16);
}
// packed pair of bf16 (lo = even col, hi = odd col) -> two floats
__device__ __forceinline__ float2 bfp2f(unsigned u) {
    float2 r;
    r.x = __uint_as_float(u << 16);
    r.y = __uint_as_float(u & 0xffff0000u);
    return r;
}

__device__ __forceinline__ f4 ntload4f(const float* p) {
    return __builtin_nontemporal_load((const f4*)p);
}

// 8 bf16 (one uint4) scaled-accumulate into acc[0..7] (static indices only)
__device__ __forceinline__ void acc8(float* acc, uint4 u, float nm) {
    const float2 p0 = bfp2f(u.x), p1 = bfp2f(u.y), p2 = bfp2f(u.z), p3 = bfp2f(u.w);
    acc[0] = fmaf(p0.x, nm, acc[0]); acc[1] = fmaf(p0.y, nm, acc[1]);
    acc[2] = fmaf(p1.x, nm, acc[2]); acc[3] = fmaf(p1.y, nm, acc[3]);
    acc[4] = fmaf(p2.x, nm, acc[4]); acc[5] = fmaf(p2.y, nm, acc[5]);
    acc[6] = fmaf(p3.x, nm, acc[6]); acc[7] = fmaf(p3.y, nm, acc[7]);
}

// ---------- weight packing helper (MFMA B-fragment order, bf16) ----------
__device__ __forceinline__ void pack_one(const float* __restrict__ W,
                                         unsigned short* __restrict__ Wp,
                                         int t, int COLS, int lg) {
    const int k = t >> lg, nn = t & (COLS - 1);
    const int kb = k >> 5, rem = k & 31, quad = rem >> 3, j = rem & 7;
    Wp[((size_t)(kb * 4 + quad) * COLS + nn) * 8 + j] = f2bf(W[t]);
}

// ---------- P1: bin edges into coarse buckets (+ fused weight packing) ----------
__global__ __launch_bounds__(256) void bin_edges(const int* __restrict__ s_ei,
                                                 const int* __restrict__ t_ei,
                                                 int* __restrict__ tail,
                                                 uint2* __restrict__ binned,
                                                 const float* __restrict__ W1,
                                                 const float* __restrict__ W2,
                                                 const float* __restrict__ W3,
                                                 unsigned short* __restrict__ Wp1,
                                                 unsigned short* __restrict__ Wp2,
                                                 unsigned short* __restrict__ W3p) {
    if (blockIdx.x >= BIN_NBLK) {   // fused weight-packing blocks
        const int idx = (blockIdx.x - BIN_NBLK) * 256 + threadIdx.x;
        if (idx < 128 * HID) {
            pack_one(W1, Wp1, idx, HID, 7);
        } else if (idx < 2 * 128 * HID) {
            pack_one(W2, Wp2, idx - 128 * HID, HID, 7);
        } else if (idx < PACK_N) {
            pack_one(W3, W3p, idx - 2 * 128 * HID, OUT_D, 6);
        }
        return;
    }

    __shared__ int hist[NBUCK];
    __shared__ int lcur[NBUCK];
    for (int i = threadIdx.x; i < NBUCK; i += 256) hist[i] = 0;
    __syncthreads();

    const int base_e = blockIdx.x * BIN_TILE;
    int esrc[16], egd[16], ebk[16];
#pragma unroll
    for (int k = 0; k < 16; ++k) {
        const int e = base_e + k * 256 + threadIdx.x;
        int s = 0, g = -1;
        if (e < N_EDGES) {
            s = s_ei[e];
            g = s_ei[N_EDGES + e];
        } else if (e < 2 * N_EDGES) {
            const int j = e - N_EDGES;
            s = t_ei[j];
            g = N_NODES + t_ei[N_EDGES + j];
        }
        esrc[k] = s; egd[k] = g;
        if (g >= 0) { ebk[k] = g >> BK_LG; atomicAdd(&hist[ebk[k]], 1); }
        else ebk[k] = -1;
    }
    __syncthreads();
    // reserve one contiguous range per (block, bucket)
    for (int i = threadIdx.x; i < NBUCK; i += 256) {
        const int h = hist[i];
        lcur[i] = h ? atomicAdd(&tail[i], h) : 0;
    }
    __syncthreads();
#pragma unroll
    for (int k = 0; k < 16; ++k) {
        if (ebk[k] >= 0) {
            const int p = atomicAdd(&lcur[ebk[k]], 1);     // LDS atomic -> global pos
            if (p < BCAP)
                binned[(size_t)ebk[k] * BCAP + p] = make_uint2((unsigned)esrc[k], (unsigned)egd[k]);
        }
    }
}

// ---------- P2: per-bucket CSR build (fixed-stride, 4-aligned node segments) ----------
__global__ __launch_bounds__(256) void build_csr(const int* __restrict__ tail,
                                                 const uint2* __restrict__ binned,
                                                 uint4* __restrict__ node_info,
                                                 float* __restrict__ dis,
                                                 int* __restrict__ ebuf) {
    __shared__ int hist[BK_W];
    __shared__ int ssum[256];
    const int b   = blockIdx.x;
    const int t   = threadIdx.x;
    const int gn0 = b << BK_LG;
    const int nn  = min(BK_W, TOTN - gn0);
    const int cnt = min(tail[b], BCAP);
    const int cbase = b * BCAP_PAD;
    const uint2* __restrict__ mine = binned + (size_t)b * BCAP;

    for (int i = t; i < BK_W; i += 256) hist[i] = 0;
    __syncthreads();
    for (int r = t; r < cnt; r += 256)
        atomicAdd(&hist[(int)mine[r].y - gn0], 1);
    __syncthreads();

    // exclusive scan over 1024 PADDED histogram entries (4 per thread, pad to x4)
    const int h0 = hist[t * 4 + 0], h1 = hist[t * 4 + 1];
    const int h2 = hist[t * 4 + 2], h3 = hist[t * 4 + 3];
    const int p0 = (h0 + 3) & ~3, p1 = (h1 + 3) & ~3;
    const int p2 = (h2 + 3) & ~3, p3 = (h3 + 3) & ~3;
    const int ts = p0 + p1 + p2 + p3;
    ssum[t] = ts;
    __syncthreads();
    for (int o = 1; o < 256; o <<= 1) {
        const int x = (t >= o) ? ssum[t - o] : 0;
        __syncthreads();
        if (t >= o) ssum[t] += x;
        __syncthreads();
    }
    const int ex = ssum[t] - ts;
    const int o0 = ex, o1 = ex + p0, o2 = o1 + p1, o3 = o2 + p2;

    // node outputs (coalesced): node_info = {off, deg, bits(dis), 0}
    if (t * 4 + 0 < nn) { const int g = gn0 + t * 4 + 0; const float d = rsqrtf((float)h0 + 1.0f);
        node_info[g] = make_uint4((unsigned)(cbase + o0), (unsigned)h0, __float_as_uint(d), 0u); dis[g] = d; }
    if (t * 4 + 1 < nn) { const int g = gn0 + t * 4 + 1; const float d = rsqrtf((float)h1 + 1.0f);
        node_info[g] = make_uint4((unsigned)(cbase + o1), (unsigned)h1, __float_as_uint(d), 0u); dis[g] = d; }
    if (t * 4 + 2 < nn) { const int g = gn0 + t * 4 + 2; const float d = rsqrtf((float)h2 + 1.0f);
        node_info[g] = make_uint4((unsigned)(cbase + o2), (unsigned)h2, __float_as_uint(d), 0u); dis[g] = d; }
    if (t * 4 + 3 < nn) { const int g = gn0 + t * 4 + 3; const float d = rsqrtf((float)h3 + 1.0f);
        node_info[g] = make_uint4((unsigned)(cbase + o3), (unsigned)h3, __float_as_uint(d), 0u); dis[g] = d; }
    __syncthreads();

    // repurpose hist as running cursors (padded exclusive offsets)
    hist[t * 4 + 0] = o0; hist[t * 4 + 1] = o1; hist[t * 4 + 2] = o2; hist[t * 4 + 3] = o3;
    __syncthreads();

    // scatter into block-local CSR window (single XCD L2)
    for (int r = t; r < cnt; r += 256) {
        const uint2 rec = mine[r];
        const int p = atomicAdd(&hist[(int)rec.y - gn0], 1);
        ebuf[cbase + p] = (int)rec.x;
    }
}

// ---------- MFMA GEMM, fp32 A (NT) with fused bf16 convert; packed B staged in LDS ----------
template <int COLS>
__global__ __launch_bounds__(256) void mfma_gemm_f32(const float* __restrict__ X0,
                                                     const float* __restrict__ X1,
                                                     const unsigned short* __restrict__ Wp0,
                                                     const unsigned short* __restrict__ Wp1,
                                                     unsigned short* __restrict__ Y0,
                                                     unsigned short* __restrict__ Y1, int n) {
    __shared__ unsigned short Bs[16 * COLS * 8];   // full packed W: 32 KB

    const float* __restrict__ X = blockIdx.y ? X1 : X0;
    const unsigned short* __restrict__ Wp = blockIdx.y ? Wp1 : Wp0;
    unsigned short* __restrict__ Y = blockIdx.y ? Y1 : Y0;

    const int wave = threadIdx.x >> 6;
    const int lane = threadIdx.x & 63;
    const int quad = lane >> 4;
    const int l16  = lane & 15;
    const int rowbase = blockIdx.x * 64 + wave * 16;
    const int row = rowbase + l16;
    const int rc  = row < n ? row : n - 1;    // clamp: garbage rows never stored

    // issue ALL 8 A-tile loads first (NT: X is read exactly once)
    f4 f[8];
    const size_t arow = (size_t)rc * 128;
#pragma unroll
    for (int i = 0; i < 8; ++i)
        f[i] = ntload4f(&X[arow + (i >> 1) * 32 + quad * 8 + (i & 1) * 4]);

    // stage packed W into LDS (uint4 copies: conflict-free)
    {
        const uint4* __restrict__ wsrc = (const uint4*)Wp;
        uint4* __restrict__ wdst = (uint4*)Bs;
        constexpr int CH = 16 * COLS;              // 16B chunks
#pragma unroll
        for (int i = 0; i < CH / 256; ++i)
            wdst[i * 256 + threadIdx.x] = wsrc[i * 256 + threadIdx.x];
    }
    __syncthreads();

    // convert A to bf16 fragments
    short8 a[4];
#pragma unroll
    for (int kb = 0; kb < 4; ++kb) {
        const f4 g0 = f[2 * kb], g1 = f[2 * kb + 1];
        short8 v;
        v[0] = (short)f2bf(g0[0]); v[1] = (short)f2bf(g0[1]);
        v[2] = (short)f2bf(g0[2]); v[3] = (short)f2bf(g0[3]);
        v[4] = (short)f2bf(g1[0]); v[5] = (short)f2bf(g1[1]);
        v[6] = (short)f2bf(g1[2]); v[7] = (short)f2bf(g1[3]);
        a[kb] = v;
    }

#pragma unroll
    for (int ct = 0; ct < COLS / 16; ++ct) {
        const int col = ct * 16 + l16;
        float4v acc = {0.0f, 0.0f, 0.0f, 0.0f};
#pragma unroll
        for (int kb = 0; kb < 4; ++kb) {
            const short8 b = *(const short8*)&Bs[((kb * 4 + quad) * COLS + col) * 8];
            acc = __builtin_amdgcn_mfma_f32_16x16x32_bf16(a[kb], b, acc, 0, 0, 0);
        }
#pragma unroll
        for (int r = 0; r < 4; ++r) {
            const int orow = rowbase + quad * 4 + r;   // C/D: row=(lane>>4)*4+reg, col=lane&15
            if (orow < n) Y[(size_t)orow * COLS + col] = f2bf(acc[r]);   // cacheable: gather target
        }
    }
}

// ---------- FUSED gather conv (128-d) + ReLU + h@W3 MFMA -> L2b directly ----------
// 16 nodes per block (exact: N % 16 == 0). 4 waves x 4 nodes, 16 lanes/node.
// Epilogue: h(bf16) -> swizzled LDS A-tile; each wave MFMAs a 16-col slice of W3.
__global__ __launch_bounds__(256) void gather_relu_mm(
        const unsigned short* __restrict__ lin0, const unsigned short* __restrict__ lin1,
        const uint4* __restrict__ node_info, const int* __restrict__ ebuf,
        const float* __restrict__ dis,
        const float* __restrict__ bias0, const float* __restrict__ bias1,
        const unsigned short* __restrict__ W3p,
        unsigned short* __restrict__ y0, unsigned short* __restrict__ y1, int n) {
    __shared__ unsigned short Bs[16 * OUT_D * 8];   // packed W3: 16 KB
    __shared__ uint4 Hs[256];                       // 16 nodes x 128 bf16, XOR-swizzled: 4 KB

    const int nodeBlocks = n / 16;
    const int net = blockIdx.x >= nodeBlocks;          // net0 blocks dispatch first
    const int bx  = blockIdx.x - net * nodeBlocks;
    const unsigned short* __restrict__ lin = net ? lin1 : lin0;
    unsigned short* __restrict__ Y = net ? y1 : y0;
    const float* __restrict__ bias = net ? bias1 : bias0;

    const int wave = threadIdx.x >> 6;
    const int lane = threadIdx.x & 63;
    const int grp  = lane >> 4;          // 4 node-groups per wave
    const int l16  = lane & 15;          // 16 lanes x uint4(16B) = 256B row
    const int nrow = wave * 4 + grp;     // block-local node row 0..15
    const int node = bx * 16 + nrow;     // always < n (exact division)

    // stage packed W3 into LDS (conflict-free uint4 copies)
    {
        const uint4* __restrict__ wsrc = (const uint4*)W3p;
        uint4* __restrict__ wdst = (uint4*)Bs;
#pragma unroll
        for (int i = 0; i < 4; ++i)      // 16KB / 16B / 256
            wdst[i * 256 + threadIdx.x] = wsrc[i * 256 + threadIdx.x];
    }

    const float* __restrict__ disb = dis + net * n;
    const uint4 ni = node_info[(size_t)net * n + node];
    const int   start = (int)ni.x;
    const int   cnt   = (int)ni.y;
    const float ds    = __uint_as_float(ni.z);
    const float inv   = ds * ds;               // 1/(deg+1)
    const uint4* __restrict__ linv = (const uint4*)lin;   // row stride: 16 uint4

    float acc[8];
    {
        const uint4 su = linv[(size_t)node * 16 + l16];
        const float2 p0 = bfp2f(su.x), p1 = bfp2f(su.y), p2 = bfp2f(su.z), p3 = bfp2f(su.w);
        acc[0] = p0.x * inv; acc[1] = p0.y * inv;
        acc[2] = p1.x * inv; acc[3] = p1.y * inv;
        acc[4] = p2.x * inv; acc[5] = p2.y * inv;
        acc[6] = p3.x * inv; acc[7] = p3.y * inv;
    }

    for (int j = 0; j < cnt; j += 8) {         // 8-deep masked batches
        const int b0 = start + j;              // 4-aligned by construction
        const int4 qa = *(const int4*)&ebuf[b0];
        const int4 qb = *(const int4*)&ebuf[b0 + 4];
        const int s0 = qa.x;
        const int s1 = j + 1 < cnt ? qa.y : qa.x;
        const int s2 = j + 2 < cnt ? qa.z : qa.x;
        const int s3 = j + 3 < cnt ? qa.w : qa.x;
        const int s4 = j + 4 < cnt ? qb.x : qa.x;
        const int s5 = j + 5 < cnt ? qb.y : qa.x;
        const int s6 = j + 6 < cnt ? qb.z : qa.x;
        const int s7 = j + 7 < cnt ? qb.w : qa.x;
        const float d0 = disb[s0], d1 = disb[s1], d2 = disb[s2], d3 = disb[s3];
        const float d4 = disb[s4], d5 = disb[s5], d6 = disb[s6], d7 = disb[s7];
        const uint4 u0 = linv[(size_t)s0 * 16 + l16];
        const uint4 u1 = linv[(size_t)s1 * 16 + l16];
        const uint4 u2 = linv[(size_t)s2 * 16 + l16];
        const uint4 u3 = linv[(size_t)s3 * 16 + l16];
        const uint4 u4 = linv[(size_t)s4 * 16 + l16];
        const uint4 u5 = linv[(size_t)s5 * 16 + l16];
        const uint4 u6 = linv[(size_t)s6 * 16 + l16];
        const uint4 u7 = linv[(size_t)s7 * 16 + l16];
        const float n0 = d0 * ds;
        const float n1 = j + 1 < cnt ? d1 * ds : 0.0f;
        const float n2 = j + 2 < cnt ? d2 * ds : 0.0f;
        const float n3 = j + 3 < cnt ? d3 * ds : 0.0f;
        const float n4 = j + 4 < cnt ? d4 * ds : 0.0f;
        const float n5 = j + 5 < cnt ? d5 * ds : 0.0f;
        const float n6 = j + 6 < cnt ? d6 * ds : 0.0f;
        const float n7 = j + 7 < cnt ? d7 * ds : 0.0f;
        acc8(acc, u0, n0); acc8(acc, u1, n1); acc8(acc, u2, n2); acc8(acc, u3, n3);
        acc8(acc, u4, n4); acc8(acc, u5, n5); acc8(acc, u6, n6); acc8(acc, u7, n7);
    }

    const float4 bb0 = ((const float4*)bias)[l16 * 2];
    const float4 bb1 = ((const float4*)bias)[l16 * 2 + 1];
    acc[0] += bb0.x; acc[1] += bb0.y; acc[2] += bb0.z; acc[3] += bb0.w;
    acc[4] += bb1.x; acc[5] += bb1.y; acc[6] += bb1.z; acc[7] += bb1.w;
#pragma unroll
    for (int k = 0; k < 8; ++k) acc[k] = acc[k] > 0.0f ? acc[k] : 0.0f;

    // h (bf16, post-ReLU) -> swizzled LDS: row=nrow, chunk c=l16 at [row*16 + (c^row)]
    uint4 hv;
    hv.x = (unsigned)f2bf(acc[0]) | ((unsigned)f2bf(acc[1]) << 16);
    hv.y = (unsigned)f2bf(acc[2]) | ((unsigned)f2bf(acc[3]) << 16);
    hv.z = (unsigned)f2bf(acc[4]) | ((unsigned)f2bf(acc[5]) << 16);
    hv.w = (unsigned)f2bf(acc[6]) | ((unsigned)f2bf(acc[7]) << 16);
    Hs[nrow * 16 + (l16 ^ nrow)] = hv;
    __syncthreads();

    // MFMA phase: A = 16-node h tile (rows=l16, k-chunk=(kb*4+quad)^swizzle),
    // B = W3 cols [wave*16, wave*16+16). 4 MFMAs over K=128.
    const int quad = lane >> 4;
    short8 a[4];
#pragma unroll
    for (int kb = 0; kb < 4; ++kb) {
        const uint4 h = Hs[l16 * 16 + ((kb * 4 + quad) ^ l16)];
        a[kb] = *(const short8*)&h;
    }
    const int col = wave * 16 + l16;
    float4v acc2 = {0.0f, 0.0f, 0.0f, 0.0f};
#pragma unroll
    for (int kb = 0; kb < 4; ++kb) {
        const short8 b = *(const short8*)&Bs[((kb * 4 + quad) * OUT_D + col) * 8];
        acc2 = __builtin_amdgcn_mfma_f32_16x16x32_bf16(a[kb], b, acc2, 0, 0, 0);
    }
#pragma unroll
    for (int r = 0; r < 4; ++r) {
        const int orow = bx * 16 + quad * 4 + r;   // C/D: row=(lane>>4)*4+reg, col=lane&15
        Y[(size_t)orow * OUT_D + col] = f2bf(acc2[r]);   // cacheable: gather_out target
    }
}

// ---------- gather conv (64-d): 8 lanes/node, 8-deep batches, net-serialized grid ----------
__global__ __launch_bounds__(256) void gather_out_64_v4(
        const unsigned short* __restrict__ lin0, const unsigned short* __restrict__ lin1,
        const uint4* __restrict__ node_info, const int* __restrict__ ebuf,
        const float* __restrict__ dis, const float* __restrict__ bias,
        float* __restrict__ out0, float* __restrict__ out1,
        unsigned short* __restrict__ zb0, unsigned short* __restrict__ zb1, int n) {
    const int nodeBlocks = (n + 31) / 32;
    const int net = blockIdx.x >= nodeBlocks;
    const int bx  = blockIdx.x - net * nodeBlocks;
    const unsigned short* __restrict__ lin = net ? lin1 : lin0;
    float* __restrict__ outp = net ? out1 : out0;
    unsigned short* __restrict__ zb = net ? zb1 : zb0;

    const int wave = threadIdx.x >> 6;
    const int lane = threadIdx.x & 63;
    const int grp  = lane >> 3;          // 8 node-groups per wave
    const int l8   = lane & 7;           // 8 lanes x uint4(16B) = 128B row
    const int node = bx * 32 + wave * 8 + grp;
    if (node >= n) return;

    const float* __restrict__ disb = dis + net * n;
    const uint4 ni = node_info[(size_t)net * n + node];
    const int   start = (int)ni.x;
    const int   cnt   = (int)ni.y;
    const float ds    = __uint_as_float(ni.z);
    const float inv   = ds * ds;
    const uint4* __restrict__ linv = (const uint4*)lin;   // row stride: 8 uint4

    float acc[8];
    {
        const uint4 su = linv[(size_t)node * 8 + l8];
        const float2 p0 = bfp2f(su.x), p1 = bfp2f(su.y), p2 = bfp2f(su.z), p3 = bfp2f(su.w);
        acc[0] = p0.x * inv; acc[1] = p0.y * inv;
        acc[2] = p1.x * inv; acc[3] = p1.y * inv;
        acc[4] = p2.x * inv; acc[5] = p2.y * inv;
        acc[6] = p3.x * inv; acc[7] = p3.y * inv;
    }

    for (int j = 0; j < cnt; j += 8) {
        const int b0 = start + j;
        const int4 qa = *(const int4*)&ebuf[b0];
        const int4 qb = *(const int4*)&ebuf[b0 + 4];
        const int s0 = qa.x;
        const int s1 = j + 1 < cnt ? qa.y : qa.x;
        const int s2 = j + 2 < cnt ? qa.z : qa.x;
        const int s3 = j + 3 < cnt ? qa.w : qa.x;
        const int s4 = j + 4 < cnt ? qb.x : qa.x;
        const int s5 = j + 5 < cnt ? qb.y : qa.x;
        const int s6 = j + 6 < cnt ? qb.z : qa.x;
        const int s7 = j + 7 < cnt ? qb.w : qa.x;
        const float d0 = disb[s0], d1 = disb[s1], d2 = disb[s2], d3 = disb[s3];
        const float d4 = disb[s4], d5 = disb[s5], d6 = disb[s6], d7 = disb[s7];
        const uint4 u0 = linv[(size_t)s0 * 8 + l8];
        const uint4 u1 = linv[(size_t)s1 * 8 + l8];
        const uint4 u2 = linv[(size_t)s2 * 8 + l8];
        const uint4 u3 = linv[(size_t)s3 * 8 + l8];
        const uint4 u4 = linv[(size_t)s4 * 8 + l8];
        const uint4 u5 = linv[(size_t)s5 * 8 + l8];
        const uint4 u6 = linv[(size_t)s6 * 8 + l8];
        const uint4 u7 = linv[(size_t)s7 * 8 + l8];
        const float n0 = d0 * ds;
        const float n1 = j + 1 < cnt ? d1 * ds : 0.0f;
        const float n2 = j + 2 < cnt ? d2 * ds : 0.0f;
        const float n3 = j + 3 < cnt ? d3 * ds : 0.0f;
        const float n4 = j + 4 < cnt ? d4 * ds : 0.0f;
        const float n5 = j + 5 < cnt ? d5 * ds : 0.0f;
        const float n6 = j + 6 < cnt ? d6 * ds : 0.0f;
        const float n7 = j + 7 < cnt ? d7 * ds : 0.0f;
        acc8(acc, u0, n0); acc8(acc, u1, n1); acc8(acc, u2, n2); acc8(acc, u3, n3);
        acc8(acc, u4, n4); acc8(acc, u5, n5); acc8(acc, u6, n6); acc8(acc, u7, n7);
    }

    const float4 bb0 = ((const float4*)bias)[l8 * 2];
    const float4 bb1 = ((const float4*)bias)[l8 * 2 + 1];
    const float z0 = acc[0] + bb0.x, z1 = acc[1] + bb0.y, z2 = acc[2] + bb0.z, z3 = acc[3] + bb0.w;
    const float z4 = acc[4] + bb1.x, z5 = acc[5] + bb1.y, z6 = acc[6] + bb1.z, z7 = acc[7] + bb1.w;

    f4 w0 = {z0, z1, z2, z3};
    f4 w1 = {z4, z5, z6, z7};
    __builtin_nontemporal_store(w0, (f4*)outp + (size_t)node * 16 + l8 * 2);      // final output
    __builtin_nontemporal_store(w1, (f4*)outp + (size_t)node * 16 + l8 * 2 + 1);

    uint4 pz;   // zb cacheable: decoder random-reads it
    pz.x = (unsigned)f2bf(z0) | ((unsigned)f2bf(z1) << 16);
    pz.y = (unsigned)f2bf(z2) | ((unsigned)f2bf(z3) << 16);
    pz.z = (unsigned)f2bf(z4) | ((unsigned)f2bf(z5) << 16);
    pz.w = (unsigned)f2bf(z6) | ((unsigned)f2bf(z7) << 16);
    ((uint4*)zb)[(size_t)node * 8 + l8] = pz;
}

// ---------- decoder (bf16 z), net-serialized grid ----------
__global__ __launch_bounds__(256) void decoder2(
        const unsigned short* __restrict__ Zb0, const unsigned short* __restrict__ Zb1,
        const int* __restrict__ s_ei, const int* __restrict__ t_ei,
        float* __restrict__ out0, float* __restrict__ out1) {
    constexpr int EBLK = (N_EDGES * 8) / 256;          // 15625 blocks per net
    const int net = blockIdx.x >= EBLK;
    const int t2  = (blockIdx.x - net * EBLK) * 256 + threadIdx.x;
    const unsigned short* __restrict__ Zb = net ? Zb1 : Zb0;
    const int* __restrict__ ei = net ? t_ei : s_ei;
    float* __restrict__ op = net ? out1 : out0;

    const int edge = t2 >> 3;   // 8 lanes per edge
    const int lane = t2 & 7;
    if (edge >= N_EDGES) return;
    const int s = __builtin_nontemporal_load(ei + edge);
    const int d = __builtin_nontemporal_load(ei + N_EDGES + edge);
    const uint4 ua = *(const uint4*)&Zb[(size_t)s * OUT_D + lane * 8];
    const uint4 ub = *(const uint4*)&Zb[(size_t)d * OUT_D + lane * 8];
    float p = 0.0f;
    {
        const float2 a0 = bfp2f(ua.x), b0 = bfp2f(ub.x);
        const float2 a1 = bfp2f(ua.y), b1 = bfp2f(ub.y);
        const float2 a2 = bfp2f(ua.z), b2 = bfp2f(ub.z);
        const float2 a3 = bfp2f(ua.w), b3 = bfp2f(ub.w);
        p = fmaf(a0.x, b0.x, p); p = fmaf(a0.y, b0.y, p);
        p = fmaf(a1.x, b1.x, p); p = fmaf(a1.y, b1.y, p);
        p = fmaf(a2.x, b2.x, p); p = fmaf(a2.y, b2.y, p);
        p = fmaf(a3.x, b3.x, p); p = fmaf(a3.y, b3.y, p);
    }
    p += __shfl_down(p, 4, 8);
    p += __shfl_down(p, 2, 8);
    p += __shfl_down(p, 1, 8);
    if (lane == 0) __builtin_nontemporal_store(1.0f / (1.0f + expf(-p)), op + edge);
}

extern "C" void kernel_launch(void* const* d_in, const int* in_sizes, int n_in,
                              void* d_out, int out_size, void* d_ws, size_t ws_size,
                              hipStream_t stream) {
    const float* xs  = (const float*)d_in[0];
    const float* xt  = (const float*)d_in[1];
    const int* s_ei  = (const int*)d_in[2];
    const int* t_ei  = (const int*)d_in[3];
    const float* W1  = (const float*)d_in[4];
    const float* b1  = (const float*)d_in[5];
    const float* W2  = (const float*)d_in[6];
    const float* b2  = (const float*)d_in[7];
    const float* W3  = (const float*)d_in[8];
    const float* b3  = (const float*)d_in[9];

    // workspace layout (~90 MB)
    unsigned short* Lb1  = (unsigned short*)d_ws;                // NPAD*128 bf16 (lin conv1, net s)
    unsigned short* Lb2  = Lb1 + (size_t)N_PAD * HID;            // NPAD*128 bf16 (lin conv1, net t)
    unsigned short* L2b1 = Lb2 + (size_t)N_PAD * HID;            // NPAD*64 bf16 (lin conv3, s)
    unsigned short* L2b2 = L2b1 + (size_t)N_PAD * OUT_D;         // NPAD*64 bf16 (lin conv3, t)
    // aliases (lifetime-disjoint):
    //   binned overlays L2b (consumed by build_csr before gather_relu_mm writes L2b)
    //   Zb overlays Lb (Lb dead after gather_relu_mm; Zb written by gather_out)
    uint2* binned        = (uint2*)L2b1;                         // NBUCK*BCAP*8B = 9.6 MB
    unsigned short* Zb1  = Lb1;
    unsigned short* Zb2  = Lb2;
    unsigned short* Wp1 = L2b2 + (size_t)N_PAD * OUT_D;          // 128*128 bf16
    unsigned short* Wp2 = Wp1 + 128 * HID;                       // 128*128 bf16
    unsigned short* W3p = Wp2 + 128 * HID;                       // 128*64 bf16
    float* dis          = (float*)(W3p + 128 * OUT_D);           // 2N f
    uint4* node_info    = (uint4*)(dis + TOTN);                  // 2N uint4
    int*   ebuf         = (int*)(node_info + TOTN);              // NBUCK*BCAP_PAD + slack
    int*   tail         = ebuf + NBUCK * BCAP_PAD + 8;           // NBUCK i

    float* out = (float*)d_out;
    float* out_zs = out;                                 // N*64
    float* out_zt = out + (size_t)N_NODES * OUT_D;       // N*64
    float* out_ps = out + 2 * (size_t)N_NODES * OUT_D;   // E
    float* out_pt = out_ps + N_EDGES;                    // E

    // ---- CSR build via bucket binning (+ fused weight pack) ----
    hipMemsetAsync(tail, 0, NBUCK * sizeof(int), stream);
    bin_edges<<<BIN_NBLK + PACK_BLK, 256, 0, stream>>>(s_ei, t_ei, tail, binned,
                                                       W1, W2, W3, Wp1, Wp2, W3p);
    build_csr<<<NBUCK, 256, 0, stream>>>(tail, binned, node_info, dis, ebuf);

    // ---- conv1/conv2 lin: fused fp32->bf16 convert + MFMA GEMM, both nets ----
    mfma_gemm_f32<HID><<<dim3(ROW_BLKS, 2), 256, 0, stream>>>(
        xs, xt, Wp1, Wp2, Lb1, Lb2, N_NODES);

    // ---- FUSED gather + bias + relu + h@W3 -> L2b (replaces gather_relu + gemm_bf) ----
    gather_relu_mm<<<2 * (N_NODES / 16), 256, 0, stream>>>(
        Lb1, Lb2, node_info, ebuf, dis, b1, b2, W3p, L2b1, L2b2, N_NODES);

    // ---- gather -> z (fp32 out) + bf16 copy ----
    gather_out_64_v4<<<2 * ((N_NODES + 31) / 32), 256, 0, stream>>>(
        L2b1, L2b2, node_info, ebuf, dis, b3, out_zs, out_zt, Zb1, Zb2, N_NODES);

    // ---- decoder ----
    decoder2<<<2 * ((N_EDGES * 8) / 256), 256, 0, stream>>>(
        Zb1, Zb2, s_ei, t_ei, out_ps, out_pt);
}

// Round 8
// 314.164 us; speedup vs baseline: 1.1163x; 1.0146x over previous
//
#include <hip/hip_runtime.h>

// Problem constants (match reference)
constexpr int N_NODES = 100000;
constexpr int N_EDGES = 500000;
constexpr int HID     = 128;   // conv1/conv2 output dim
constexpr int OUT_D   = 64;    // conv3 output dim
constexpr int TOTN    = 2 * N_NODES;   // both networks concatenated

constexpr int ROW_BLKS = (N_NODES + 63) / 64;   // 1563 blocks of 64 rows
constexpr int N_PAD    = ROW_BLKS * 64;          // 100032 padded rows
static_assert(N_NODES % 16 == 0, "fused gather+MM needs exact 16-node blocks");
static_assert(N_PAD - N_NODES == 32, "dis pad region sized for 32 rows");

// ---- CSR build via coarse bucket binning ----
constexpr int BK_LG    = 10;                      // 1024 nodes per bucket
constexpr int BK_W     = 1 << BK_LG;
constexpr int NBUCK    = (TOTN + BK_W - 1) >> BK_LG;   // 196
constexpr int BCAP     = 6144;                    // mean 5120, sigma~72 -> +14 sigma
constexpr int BCAP_PAD = BCAP + 7 * BK_W;         // 13312: room for per-node 8-align padding
constexpr int BIN_TILE = 4096;                    // edges per bin block
constexpr int BIN_NBLK = (2 * N_EDGES + BIN_TILE - 1) / BIN_TILE;  // 245
constexpr int PACK_N   = 2 * 128 * HID + 128 * OUT_D;              // 40960 weight elems
constexpr int PACK_BLK = (PACK_N + 255) / 256;                     // 160
static_assert(NBUCK <= 256, "bucket scan must fit one block");

typedef __attribute__((ext_vector_type(8))) short short8;
typedef __attribute__((ext_vector_type(4))) float float4v;
typedef __attribute__((ext_vector_type(4))) float f4;

// float -> bf16 (round-to-nearest-even), as raw ushort
__device__ __forceinline__ unsigned short f2bf(float f) {
    unsigned u = __float_as_uint(f);
    u += 0x7fffu + ((u >> 16) & 1u);
    return (unsigned short)(u >> 16);
}
// packed pair of bf16 (lo = even col, hi = odd col) -> two floats
__device__ __forceinline__ float2 bfp2f(unsigned u) {
    float2 r;
    r.x = __uint_as_float(u << 16);
    r.y = __uint_as_float(u & 0xffff0000u);
    return r;
}

__device__ __forceinline__ f4 ntload4f(const float* p) {
    return __builtin_nontemporal_load((const f4*)p);
}

// 8 bf16 (one uint4) scaled-accumulate into acc[0..7] (static indices only)
__device__ __forceinline__ void acc8(float* acc, uint4 u, float nm) {
    const float2 p0 = bfp2f(u.x), p1 = bfp2f(u.y), p2 = bfp2f(u.z), p3 = bfp2f(u.w);
    acc[0] = fmaf(p0.x, nm, acc[0]); acc[1] = fmaf(p0.y, nm, acc[1]);
    acc[2] = fmaf(p1.x, nm, acc[2]); acc[3] = fmaf(p1.y, nm, acc[3]);
    acc[4] = fmaf(p2.x, nm, acc[4]); acc[5] = fmaf(p2.y, nm, acc[5]);
    acc[6] = fmaf(p3.x, nm, acc[6]); acc[7] = fmaf(p3.y, nm, acc[7]);
}

// ---------- weight packing helper (MFMA B-fragment order, bf16) ----------
__device__ __forceinline__ void pack_one(const float* __restrict__ W,
                                         unsigned short* __restrict__ Wp,
                                         int t, int COLS, int lg) {
    const int k = t >> lg, nn = t & (COLS - 1);
    const int kb = k >> 5, rem = k & 31, quad = rem >> 3, j = rem & 7;
    Wp[((size_t)(kb * 4 + quad) * COLS + nn) * 8 + j] = f2bf(W[t]);
}

// ---------- P1: bin edges into coarse buckets (+ weight pack + dis-pad zero) ----------
__global__ __launch_bounds__(256) void bin_edges(const int* __restrict__ s_ei,
                                                 const int* __restrict__ t_ei,
                                                 int* __restrict__ tail,
                                                 uint2* __restrict__ binned,
                                                 const float* __restrict__ W1,
                                                 const float* __restrict__ W2,
                                                 const float* __restrict__ W3,
                                                 unsigned short* __restrict__ Wp1,
                                                 unsigned short* __restrict__ Wp2,
                                                 unsigned short* __restrict__ W3p,
                                                 float* __restrict__ dis) {
    if (blockIdx.x >= BIN_NBLK) {   // fused weight-packing blocks
        if (blockIdx.x == BIN_NBLK && threadIdx.x < 64) {
            // zero dis pad regions [N_NODES, N_PAD) for both nets (sentinel norm = 0)
            const int i = threadIdx.x;
            if (i < 32) dis[N_NODES + i] = 0.0f;
            else        dis[N_PAD + N_NODES + (i - 32)] = 0.0f;
        }
        const int idx = (blockIdx.x - BIN_NBLK) * 256 + threadIdx.x;
        if (idx < 128 * HID) {
            pack_one(W1, Wp1, idx, HID, 7);
        } else if (idx < 2 * 128 * HID) {
            pack_one(W2, Wp2, idx - 128 * HID, HID, 7);
        } else if (idx < PACK_N) {
            pack_one(W3, W3p, idx - 2 * 128 * HID, OUT_D, 6);
        }
        return;
    }

    __shared__ int hist[NBUCK];
    __shared__ int lcur[NBUCK];
    for (int i = threadIdx.x; i < NBUCK; i += 256) hist[i] = 0;
    __syncthreads();

    const int base_e = blockIdx.x * BIN_TILE;
    int esrc[16], egd[16], ebk[16];
#pragma unroll
    for (int k = 0; k < 16; ++k) {
        const int e = base_e + k * 256 + threadIdx.x;
        int s = 0, g = -1;
        if (e < N_EDGES) {
            s = s_ei[e];
            g = s_ei[N_EDGES + e];
        } else if (e < 2 * N_EDGES) {
            const int j = e - N_EDGES;
            s = t_ei[j];
            g = N_NODES + t_ei[N_EDGES + j];
        }
        esrc[k] = s; egd[k] = g;
        if (g >= 0) { ebk[k] = g >> BK_LG; atomicAdd(&hist[ebk[k]], 1); }
        else ebk[k] = -1;
    }
    __syncthreads();
    // reserve one contiguous range per (block, bucket)
    for (int i = threadIdx.x; i < NBUCK; i += 256) {
        const int h = hist[i];
        lcur[i] = h ? atomicAdd(&tail[i], h) : 0;
    }
    __syncthreads();
#pragma unroll
    for (int k = 0; k < 16; ++k) {
        if (ebk[k] >= 0) {
            const int p = atomicAdd(&lcur[ebk[k]], 1);     // LDS atomic -> global pos
            if (p < BCAP)
                binned[(size_t)ebk[k] * BCAP + p] = make_uint2((unsigned)esrc[k], (unsigned)egd[k]);
        }
    }
}

// ================= P2 fused: per-bucket CSR build + conv1/conv2 MFMA GEMM =================
// Blocks [0, NBUCK): CSR build (8-aligned node segments, sentinel-padded).
// Blocks [NBUCK, NBUCK + 2*ROW_BLKS): fp32-A MFMA GEMM with fused bf16 convert.
__global__ __launch_bounds__(256) void csr_gemm(const int* __restrict__ tail,
                                                const uint2* __restrict__ binned,
                                                uint4* __restrict__ node_info,
                                                float* __restrict__ dis,
                                                int* __restrict__ ebuf,
                                                const float* __restrict__ X0,
                                                const float* __restrict__ X1,
                                                const unsigned short* __restrict__ Wp0,
                                                const unsigned short* __restrict__ Wp1,
                                                unsigned short* __restrict__ Y0,
                                                unsigned short* __restrict__ Y1, int n) {
    __shared__ char smraw[16 * HID * 8 * 2];   // 32 KB, shared by both branches

    if (blockIdx.x < NBUCK) {
        // -------- CSR build branch --------
        int* hist = (int*)smraw;                 // BK_W ints
        int* ssum = (int*)smraw + BK_W;          // 256 ints
        const int b   = blockIdx.x;
        const int t   = threadIdx.x;
        const int gn0 = b << BK_LG;
        const int nn  = min(BK_W, TOTN - gn0);
        const int cnt = min(tail[b], BCAP);
        const int cbase = b * BCAP_PAD;
        const uint2* __restrict__ mine = binned + (size_t)b * BCAP;

        for (int i = t; i < BK_W; i += 256) hist[i] = 0;
        __syncthreads();
        for (int r = t; r < cnt; r += 256)
            atomicAdd(&hist[(int)mine[r].y - gn0], 1);
        __syncthreads();

        // exclusive scan over 1024 entries padded to x8 (4 per thread)
        const int h0 = hist[t * 4 + 0], h1 = hist[t * 4 + 1];
        const int h2 = hist[t * 4 + 2], h3 = hist[t * 4 + 3];
        const int p0 = (h0 + 7) & ~7, p1 = (h1 + 7) & ~7;
        const int p2 = (h2 + 7) & ~7, p3 = (h3 + 7) & ~7;
        const int ts = p0 + p1 + p2 + p3;
        ssum[t] = ts;
        __syncthreads();
        for (int o = 1; o < 256; o <<= 1) {
            const int x = (t >= o) ? ssum[t - o] : 0;
            __syncthreads();
            if (t >= o) ssum[t] += x;
            __syncthreads();
        }
        const int ex = ssum[t] - ts;
        const int o0 = ex, o1 = ex + p0, o2 = o1 + p1, o3 = o2 + p2;

        // node outputs: node_info = {off, deg, bits(dis), 0}; dis with per-net stride N_PAD
#define EMIT(K, OK, HK)                                                                  \
        if (t * 4 + K < nn) {                                                            \
            const int g = gn0 + t * 4 + K;                                               \
            const float d = rsqrtf((float)HK + 1.0f);                                    \
            node_info[g] = make_uint4((unsigned)(cbase + OK), (unsigned)HK,              \
                                      __float_as_uint(d), 0u);                           \
            dis[g + (g >= N_NODES ? (N_PAD - N_NODES) : 0)] = d;                         \
        }
        EMIT(0, o0, h0) EMIT(1, o1, h1) EMIT(2, o2, h2) EMIT(3, o3, h3)
#undef EMIT
        __syncthreads();

        // repurpose hist as running cursors (padded exclusive offsets)
        hist[t * 4 + 0] = o0; hist[t * 4 + 1] = o1; hist[t * 4 + 2] = o2; hist[t * 4 + 3] = o3;
        __syncthreads();

        // scatter into block-local CSR window (single XCD L2)
        for (int r = t; r < cnt; r += 256) {
            const uint2 rec = mine[r];
            const int p = atomicAdd(&hist[(int)rec.y - gn0], 1);
            ebuf[cbase + p] = (int)rec.x;
        }

        // sentinel-fill pad slots: src = N_NODES (dis = 0, finite lin row)
#define PADFILL(K, OK, HK, PK)                                                           \
        if (t * 4 + K < nn) {                                                            \
            for (int q = HK; q < PK; ++q) ebuf[cbase + OK + q] = N_NODES;                \
        }
        PADFILL(0, o0, h0, p0) PADFILL(1, o1, h1, p1)
        PADFILL(2, o2, h2, p2) PADFILL(3, o3, h3, p3)
#undef PADFILL
        return;
    }

    // -------- GEMM branch (fp32 A, fused bf16 convert; packed B staged in LDS) --------
    unsigned short* Bs = (unsigned short*)smraw;   // 16*HID*8 bf16 = 32 KB
    const int cbid = blockIdx.x - NBUCK;
    const int net  = cbid >= ROW_BLKS;
    const int xb   = net ? cbid - ROW_BLKS : cbid;
    const float* __restrict__ X = net ? X1 : X0;
    const unsigned short* __restrict__ Wp = net ? Wp1 : Wp0;
    unsigned short* __restrict__ Y = net ? Y1 : Y0;

    const int wave = threadIdx.x >> 6;
    const int lane = threadIdx.x & 63;
    const int quad = lane >> 4;
    const int l16  = lane & 15;
    const int rowbase = xb * 64 + wave * 16;
    const int row = rowbase + l16;
    const int rc  = row < n ? row : n - 1;    // clamp: pad rows get finite duplicates

    // issue ALL 8 A-tile loads first (NT: X is read exactly once)
    f4 f[8];
    const size_t arow = (size_t)rc * 128;
#pragma unroll
    for (int i = 0; i < 8; ++i)
        f[i] = ntload4f(&X[arow + (i >> 1) * 32 + quad * 8 + (i & 1) * 4]);

    // stage packed W into LDS (uint4 copies: conflict-free)
    {
        const uint4* __restrict__ wsrc = (const uint4*)Wp;
        uint4* __restrict__ wdst = (uint4*)Bs;
#pragma unroll
        for (int i = 0; i < 16 * HID / 256; ++i)
            wdst[i * 256 + threadIdx.x] = wsrc[i * 256 + threadIdx.x];
    }
    __syncthreads();

    // convert A to bf16 fragments
    short8 a[4];
#pragma unroll
    for (int kb = 0; kb < 4; ++kb) {
        const f4 g0 = f[2 * kb], g1 = f[2 * kb + 1];
        short8 v;
        v[0] = (short)f2bf(g0[0]); v[1] = (short)f2bf(g0[1]);
        v[2] = (short)f2bf(g0[2]); v[3] = (short)f2bf(g0[3]);
        v[4] = (short)f2bf(g1[0]); v[5] = (short)f2bf(g1[1]);
        v[6] = (short)f2bf(g1[2]); v[7] = (short)f2bf(g1[3]);
        a[kb] = v;
    }

#pragma unroll
    for (int ct = 0; ct < HID / 16; ++ct) {
        const int col = ct * 16 + l16;
        float4v acc = {0.0f, 0.0f, 0.0f, 0.0f};
#pragma unroll
        for (int kb = 0; kb < 4; ++kb) {
            const short8 b = *(const short8*)&Bs[((kb * 4 + quad) * HID + col) * 8];
            acc = __builtin_amdgcn_mfma_f32_16x16x32_bf16(a[kb], b, acc, 0, 0, 0);
        }
#pragma unroll
        for (int r = 0; r < 4; ++r) {
            const int orow = rowbase + quad * 4 + r;   // C/D: row=(lane>>4)*4+reg, col=lane&15
            Y[(size_t)orow * HID + col] = f2bf(acc[r]);  // write ALL N_PAD rows (finite)
        }
    }
}

// ---------- FUSED gather conv (128-d) + ReLU + h@W3 MFMA -> L2b (branchless inner loop) ----------
__global__ __launch_bounds__(256) void gather_relu_mm(
        const unsigned short* __restrict__ lin0, const unsigned short* __restrict__ lin1,
        const uint4* __restrict__ node_info, const int* __restrict__ ebuf,
        const float* __restrict__ dis,
        const float* __restrict__ bias0, const float* __restrict__ bias1,
        const unsigned short* __restrict__ W3p,
        unsigned short* __restrict__ y0, unsigned short* __restrict__ y1, int n) {
    __shared__ unsigned short Bs[16 * OUT_D * 8];   // packed W3: 16 KB
    __shared__ uint4 Hs[256];                       // 16 nodes x 128 bf16, XOR-swizzled: 4 KB

    const int nodeBlocks = n / 16;
    if (blockIdx.x == 2 * nodeBlocks) {   // pad-row fill block: zero L2b rows [n, N_PAD)
        const uint4 z = make_uint4(0u, 0u, 0u, 0u);
        ((uint4*)(y0 + (size_t)n * OUT_D))[threadIdx.x] = z;   // 256 x 16B = 32 rows x 64 bf16
        ((uint4*)(y1 + (size_t)n * OUT_D))[threadIdx.x] = z;
        return;
    }
    const int net = blockIdx.x >= nodeBlocks;          // net0 blocks dispatch first
    const int bx  = blockIdx.x - net * nodeBlocks;
    const unsigned short* __restrict__ lin = net ? lin1 : lin0;
    unsigned short* __restrict__ Y = net ? y1 : y0;
    const float* __restrict__ bias = net ? bias1 : bias0;

    const int wave = threadIdx.x >> 6;
    const int lane = threadIdx.x & 63;
    const int grp  = lane >> 4;          // 4 node-groups per wave
    const int l16  = lane & 15;          // 16 lanes x uint4(16B) = 256B row
    const int nrow = wave * 4 + grp;     // block-local node row 0..15
    const int node = bx * 16 + nrow;     // always < n (exact division)

    // stage packed W3 into LDS (conflict-free uint4 copies)
    {
        const uint4* __restrict__ wsrc = (const uint4*)W3p;
        uint4* __restrict__ wdst = (uint4*)Bs;
#pragma unroll
        for (int i = 0; i < 4; ++i)
            wdst[i * 256 + threadIdx.x] = wsrc[i * 256 + threadIdx.x];
    }

    const float* __restrict__ disb = dis + net * N_PAD;   // pad entries read dis=0
    const uint4 ni = node_info[(size_t)net * n + node];
    const int   start = (int)ni.x;
    const int   cnt   = (int)ni.y;
    const float ds    = __uint_as_float(ni.z);
    const float inv   = ds * ds;               // 1/(deg+1)
    const uint4* __restrict__ linv = (const uint4*)lin;   // row stride: 16 uint4

    float acc[8];
    {
        const uint4 su = linv[(size_t)node * 16 + l16];
        const float2 p0 = bfp2f(su.x), p1 = bfp2f(su.y), p2 = bfp2f(su.z), p3 = bfp2f(su.w);
        acc[0] = p0.x * inv; acc[1] = p0.y * inv;
        acc[2] = p1.x * inv; acc[3] = p1.y * inv;
        acc[4] = p2.x * inv; acc[5] = p2.y * inv;
        acc[6] = p3.x * inv; acc[7] = p3.y * inv;
    }

    for (int j = 0; j < cnt; j += 8) {         // branchless: list is sentinel-padded to x8
        const int b0 = start + j;              // 8-aligned by construction
        const int4 qa = *(const int4*)&ebuf[b0];
        const int4 qb = *(const int4*)&ebuf[b0 + 4];
        const float d0 = disb[qa.x], d1 = disb[qa.y], d2 = disb[qa.z], d3 = disb[qa.w];
        const float d4 = disb[qb.x], d5 = disb[qb.y], d6 = disb[qb.z], d7 = disb[qb.w];
        const uint4 u0 = linv[(size_t)qa.x * 16 + l16];
        const uint4 u1 = linv[(size_t)qa.y * 16 + l16];
        const uint4 u2 = linv[(size_t)qa.z * 16 + l16];
        const uint4 u3 = linv[(size_t)qa.w * 16 + l16];
        const uint4 u4 = linv[(size_t)qb.x * 16 + l16];
        const uint4 u5 = linv[(size_t)qb.y * 16 + l16];
        const uint4 u6 = linv[(size_t)qb.z * 16 + l16];
        const uint4 u7 = linv[(size_t)qb.w * 16 + l16];
        acc8(acc, u0, d0 * ds); acc8(acc, u1, d1 * ds);
        acc8(acc, u2, d2 * ds); acc8(acc, u3, d3 * ds);
        acc8(acc, u4, d4 * ds); acc8(acc, u5, d5 * ds);
        acc8(acc, u6, d6 * ds); acc8(acc, u7, d7 * ds);
    }

    const float4 bb0 = ((const float4*)bias)[l16 * 2];
    const float4 bb1 = ((const float4*)bias)[l16 * 2 + 1];
    acc[0] += bb0.x; acc[1] += bb0.y; acc[2] += bb0.z; acc[3] += bb0.w;
    acc[4] += bb1.x; acc[5] += bb1.y; acc[6] += bb1.z; acc[7] += bb1.w;
#pragma unroll
    for (int k = 0; k < 8; ++k) acc[k] = acc[k] > 0.0f ? acc[k] : 0.0f;

    // h (bf16, post-ReLU) -> swizzled LDS: row=nrow, chunk c=l16 at [row*16 + (c^row)]
    uint4 hv;
    hv.x = (unsigned)f2bf(acc[0]) | ((unsigned)f2bf(acc[1]) << 16);
    hv.y = (unsigned)f2bf(acc[2]) | ((unsigned)f2bf(acc[3]) << 16);
    hv.z = (unsigned)f2bf(acc[4]) | ((unsigned)f2bf(acc[5]) << 16);
    hv.w = (unsigned)f2bf(acc[6]) | ((unsigned)f2bf(acc[7]) << 16);
    Hs[nrow * 16 + (l16 ^ nrow)] = hv;
    __syncthreads();

    // MFMA phase: A = 16-node h tile, B = W3 cols [wave*16, wave*16+16). K=128.
    const int quad = lane >> 4;
    short8 a[4];
#pragma unroll
    for (int kb = 0; kb < 4; ++kb) {
        const uint4 h = Hs[l16 * 16 + ((kb * 4 + quad) ^ l16)];
        a[kb] = *(const short8*)&h;
    }
    const int col = wave * 16 + l16;
    float4v acc2 = {0.0f, 0.0f, 0.0f, 0.0f};
#pragma unroll
    for (int kb = 0; kb < 4; ++kb) {
        const short8 b = *(const short8*)&Bs[((kb * 4 + quad) * OUT_D + col) * 8];
        acc2 = __builtin_amdgcn_mfma_f32_16x16x32_bf16(a[kb], b, acc2, 0, 0, 0);
    }
#pragma unroll
    for (int r = 0; r < 4; ++r) {
        const int orow = bx * 16 + quad * 4 + r;   // C/D: row=(lane>>4)*4+reg, col=lane&15
        Y[(size_t)orow * OUT_D + col] = f2bf(acc2[r]);
    }
}

// ---------- gather conv (64-d): 8 lanes/node, branchless 8-deep batches ----------
__global__ __launch_bounds__(256) void gather_out_64_v5(
        const unsigned short* __restrict__ lin0, const unsigned short* __restrict__ lin1,
        const uint4* __restrict__ node_info, const int* __restrict__ ebuf,
        const float* __restrict__ dis, const float* __restrict__ bias,
        float* __restrict__ out0, float* __restrict__ out1,
        unsigned short* __restrict__ zb0, unsigned short* __restrict__ zb1, int n) {
    const int nodeBlocks = (n + 31) / 32;
    const int net = blockIdx.x >= nodeBlocks;
    const int bx  = blockIdx.x - net * nodeBlocks;
    const unsigned short* __restrict__ lin = net ? lin1 : lin0;
    float* __restrict__ outp = net ? out1 : out0;
    unsigned short* __restrict__ zb = net ? zb1 : zb0;

    const int wave = threadIdx.x >> 6;
    const int lane = threadIdx.x & 63;
    const int grp  = lane >> 3;          // 8 node-groups per wave
    const int l8   = lane & 7;           // 8 lanes x uint4(16B) = 128B row
    const int node = bx * 32 + wave * 8 + grp;
    if (node >= n) return;

    const float* __restrict__ disb = dis + net * N_PAD;   // pad entries read dis=0
    const uint4 ni = node_info[(size_t)net * n + node];
    const int   start = (int)ni.x;
    const int   cnt   = (int)ni.y;
    const float ds    = __uint_as_float(ni.z);
    const float inv   = ds * ds;
    const uint4* __restrict__ linv = (const uint4*)lin;   // row stride: 8 uint4

    float acc[8];
    {
        const uint4 su = linv[(size_t)node * 8 + l8];
        const float2 p0 = bfp2f(su.x), p1 = bfp2f(su.y), p2 = bfp2f(su.z), p3 = bfp2f(su.w);
        acc[0] = p0.x * inv; acc[1] = p0.y * inv;
        acc[2] = p1.x * inv; acc[3] = p1.y * inv;
        acc[4] = p2.x * inv; acc[5] = p2.y * inv;
        acc[6] = p3.x * inv; acc[7] = p3.y * inv;
    }

    for (int j = 0; j < cnt; j += 8) {       // branchless: sentinel-padded (pad rows are zero)
        const int b0 = start + j;
        const int4 qa = *(const int4*)&ebuf[b0];
        const int4 qb = *(const int4*)&ebuf[b0 + 4];
        const float d0 = disb[qa.x], d1 = disb[qa.y], d2 = disb[qa.z], d3 = disb[qa.w];
        const float d4 = disb[qb.x], d5 = disb[qb.y], d6 = disb[qb.z], d7 = disb[qb.w];
        const uint4 u0 = linv[(size_t)qa.x * 8 + l8];
        const uint4 u1 = linv[(size_t)qa.y * 8 + l8];
        const uint4 u2 = linv[(size_t)qa.z * 8 + l8];
        const uint4 u3 = linv[(size_t)qa.w * 8 + l8];
        const uint4 u4 = linv[(size_t)qb.x * 8 + l8];
        const uint4 u5 = linv[(size_t)qb.y * 8 + l8];
        const uint4 u6 = linv[(size_t)qb.z * 8 + l8];
        const uint4 u7 = linv[(size_t)qb.w * 8 + l8];
        acc8(acc, u0, d0 * ds); acc8(acc, u1, d1 * ds);
        acc8(acc, u2, d2 * ds); acc8(acc, u3, d3 * ds);
        acc8(acc, u4, d4 * ds); acc8(acc, u5, d5 * ds);
        acc8(acc, u6, d6 * ds); acc8(acc, u7, d7 * ds);
    }

    const float4 bb0 = ((const float4*)bias)[l8 * 2];
    const float4 bb1 = ((const float4*)bias)[l8 * 2 + 1];
    const float z0 = acc[0] + bb0.x, z1 = acc[1] + bb0.y, z2 = acc[2] + bb0.z, z3 = acc[3] + bb0.w;
    const float z4 = acc[4] + bb1.x, z5 = acc[5] + bb1.y, z6 = acc[6] + bb1.z, z7 = acc[7] + bb1.w;

    f4 w0 = {z0, z1, z2, z3};
    f4 w1 = {z4, z5, z6, z7};
    __builtin_nontemporal_store(w0, (f4*)outp + (size_t)node * 16 + l8 * 2);      // final output
    __builtin_nontemporal_store(w1, (f4*)outp + (size_t)node * 16 + l8 * 2 + 1);

    uint4 pz;   // zb cacheable: decoder random-reads it
    pz.x = (unsigned)f2bf(z0) | ((unsigned)f2bf(z1) << 16);
    pz.y = (unsigned)f2bf(z2) | ((unsigned)f2bf(z3) << 16);
    pz.z = (unsigned)f2bf(z4) | ((unsigned)f2bf(z5) << 16);
    pz.w = (unsigned)f2bf(z6) | ((unsigned)f2bf(z7) << 16);
    ((uint4*)zb)[(size_t)node * 8 + l8] = pz;
}

// ---------- decoder (bf16 z), net-serialized grid ----------
__global__ __launch_bounds__(256) void decoder2(
        const unsigned short* __restrict__ Zb0, const unsigned short* __restrict__ Zb1,
        const int* __restrict__ s_ei, const int* __restrict__ t_ei,
        float* __restrict__ out0, float* __restrict__ out1) {
    constexpr int EBLK = (N_EDGES * 8) / 256;          // 15625 blocks per net
    const int net = blockIdx.x >= EBLK;
    const int t2  = (blockIdx.x - net * EBLK) * 256 + threadIdx.x;
    const unsigned short* __restrict__ Zb = net ? Zb1 : Zb0;
    const int* __restrict__ ei = net ? t_ei : s_ei;
    float* __restrict__ op = net ? out1 : out0;

    const int edge = t2 >> 3;   // 8 lanes per edge
    const int lane = t2 & 7;
    if (edge >= N_EDGES) return;
    const int s = __builtin_nontemporal_load(ei + edge);
    const int d = __builtin_nontemporal_load(ei + N_EDGES + edge);
    const uint4 ua = *(const uint4*)&Zb[(size_t)s * OUT_D + lane * 8];
    const uint4 ub = *(const uint4*)&Zb[(size_t)d * OUT_D + lane * 8];
    float p = 0.0f;
    {
        const float2 a0 = bfp2f(ua.x), b0 = bfp2f(ub.x);
        const float2 a1 = bfp2f(ua.y), b1 = bfp2f(ub.y);
        const float2 a2 = bfp2f(ua.z), b2 = bfp2f(ub.z);
        const float2 a3 = bfp2f(ua.w), b3 = bfp2f(ub.w);
        p = fmaf(a0.x, b0.x, p); p = fmaf(a0.y, b0.y, p);
        p = fmaf(a1.x, b1.x, p); p = fmaf(a1.y, b1.y, p);
        p = fmaf(a2.x, b2.x, p); p = fmaf(a2.y, b2.y, p);
        p = fmaf(a3.x, b3.x, p); p = fmaf(a3.y, b3.y, p);
    }
    p += __shfl_down(p, 4, 8);
    p += __shfl_down(p, 2, 8);
    p += __shfl_down(p, 1, 8);
    if (lane == 0) __builtin_nontemporal_store(1.0f / (1.0f + expf(-p)), op + edge);
}

extern "C" void kernel_launch(void* const* d_in, const int* in_sizes, int n_in,
                              void* d_out, int out_size, void* d_ws, size_t ws_size,
                              hipStream_t stream) {
    const float* xs  = (const float*)d_in[0];
    const float* xt  = (const float*)d_in[1];
    const int* s_ei  = (const int*)d_in[2];
    const int* t_ei  = (const int*)d_in[3];
    const float* W1  = (const float*)d_in[4];
    const float* b1  = (const float*)d_in[5];
    const float* W2  = (const float*)d_in[6];
    const float* b2  = (const float*)d_in[7];
    const float* W3  = (const float*)d_in[8];
    const float* b3  = (const float*)d_in[9];

    // workspace layout (~92 MB)
    unsigned short* Lb1  = (unsigned short*)d_ws;                // NPAD*128 bf16 (lin conv1, net s)
    unsigned short* Lb2  = Lb1 + (size_t)N_PAD * HID;            // NPAD*128 bf16 (lin conv1, net t)
    unsigned short* L2b1 = Lb2 + (size_t)N_PAD * HID;            // NPAD*64 bf16 (lin conv3, s)
    unsigned short* L2b2 = L2b1 + (size_t)N_PAD * OUT_D;         // NPAD*64 bf16 (lin conv3, t)
    // aliases (lifetime-disjoint):
    //   binned overlays L2b (consumed by csr_gemm's build branch before gather writes L2b)
    //   Zb overlays Lb (Lb dead after gather_relu_mm)
    uint2* binned        = (uint2*)L2b1;                         // NBUCK*BCAP*8B = 9.6 MB
    unsigned short* Zb1  = Lb1;
    unsigned short* Zb2  = Lb2;
    unsigned short* Wp1 = L2b2 + (size_t)N_PAD * OUT_D;          // 128*128 bf16
    unsigned short* Wp2 = Wp1 + 128 * HID;                       // 128*128 bf16
    unsigned short* W3p = Wp2 + 128 * HID;                       // 128*64 bf16
    float* dis          = (float*)(W3p + 128 * OUT_D);           // 2*N_PAD f (pad tails = 0)
    uint4* node_info    = (uint4*)(dis + 2 * N_PAD);             // 2N uint4
    int*   ebuf         = (int*)(node_info + TOTN);              // NBUCK*BCAP_PAD
    int*   tail         = ebuf + NBUCK * BCAP_PAD + 8;           // NBUCK i

    float* out = (float*)d_out;
    float* out_zs = out;                                 // N*64
    float* out_zt = out + (size_t)N_NODES * OUT_D;       // N*64
    float* out_ps = out + 2 * (size_t)N_NODES * OUT_D;   // E
    float* out_pt = out_ps + N_EDGES;                    // E

    // ---- CSR binning (+ weight pack + dis-pad zero) ----
    hipMemsetAsync(tail, 0, NBUCK * sizeof(int), stream);
    bin_edges<<<BIN_NBLK + PACK_BLK, 256, 0, stream>>>(s_ei, t_ei, tail, binned,
                                                       W1, W2, W3, Wp1, Wp2, W3p, dis);

    // ---- fused: CSR finalize + conv1/conv2 MFMA GEMM ----
    csr_gemm<<<NBUCK + 2 * ROW_BLKS, 256, 0, stream>>>(
        tail, binned, node_info, dis, ebuf, xs, xt, Wp1, Wp2, Lb1, Lb2, N_NODES);

    // ---- FUSED gather + bias + relu + h@W3 -> L2b (+1 pad-fill block) ----
    gather_relu_mm<<<2 * (N_NODES / 16) + 1, 256, 0, stream>>>(
        Lb1, Lb2, node_info, ebuf, dis, b1, b2, W3p, L2b1, L2b2, N_NODES);

    // ---- gather -> z (fp32 out) + bf16 copy ----
    gather_out_64_v5<<<2 * ((N_NODES + 31) / 32), 256, 0, stream>>>(
        L2b1, L2b2, node_info, ebuf, dis, b3, out_zs, out_zt, Zb1, Zb2, N_NODES);

    // ---- decoder ----
    decoder2<<<2 * ((N_EDGES * 8) / 256), 256, 0, stream>>>(
        Zb1, Zb2, s_ei, t_ei, out_ps, out_pt);
}